// Round 1
// baseline (792.022 us; speedup 1.0000x reference)
//
#include <hip/hip_runtime.h>
#include <cstddef>

constexpr int NPTS   = 524288;
constexpr int NG     = 16;
constexpr int GR     = 64;
constexpr int GR3    = GR * GR * GR;   // 262144
constexpr int DIN    = 32;
constexpr int NNODES = 64;

__global__ __launch_bounds__(256) void amgsrn_fused(
    const float* __restrict__ xs,
    const float* __restrict__ rot,
    const float* __restrict__ scl,
    const float* __restrict__ trn,
    const float* __restrict__ grids,
    const float* __restrict__ W0,
    const float* __restrict__ b0,
    const float* __restrict__ W1,
    const float* __restrict__ b1,
    const float* __restrict__ W2,
    const float* __restrict__ b2,
    float* __restrict__ out)
{
    __shared__ float sM[NG][12];
    const int tid = threadIdx.x;
    if (tid < NG) {
        const int g = tid;
        float qx = rot[g*4+0], qy = rot[g*4+1], qz = rot[g*4+2], qw = rot[g*4+3];
        const float inv = 1.0f / sqrtf(qx*qx + qy*qy + qz*qz + qw*qw);
        qx *= inv; qy *= inv; qz *= inv; qw *= inv;
        const float sx = expf(scl[g*3+0]);
        const float sy = expf(scl[g*3+1]);
        const float sz = expf(scl[g*3+2]);
        sM[g][0] = sx * (1.0f - 2.0f*(qy*qy + qz*qz));
        sM[g][1] = sx * (2.0f*(qx*qy - qz*qw));
        sM[g][2] = sx * (2.0f*(qx*qz + qy*qw));
        sM[g][3] = sy * (2.0f*(qx*qy + qz*qw));
        sM[g][4] = sy * (1.0f - 2.0f*(qx*qx + qz*qz));
        sM[g][5] = sy * (2.0f*(qy*qz - qx*qw));
        sM[g][6] = sz * (2.0f*(qx*qz - qy*qw));
        sM[g][7] = sz * (2.0f*(qy*qz + qx*qw));
        sM[g][8] = sz * (1.0f - 2.0f*(qx*qx + qy*qy));
        sM[g][9]  = trn[g*3+0];
        sM[g][10] = trn[g*3+1];
        sM[g][11] = trn[g*3+2];
    }
    __syncthreads();

    const int n = blockIdx.x * blockDim.x + tid;
    if (n >= NPTS) return;
    const float px = xs[n*3+0];
    const float py = xs[n*3+1];
    const float pz = xs[n*3+2];

    float feats[DIN];

    #pragma unroll
    for (int g = 0; g < NG; ++g) {
        const float* m = sM[g];
        const float tx = m[0]*px + m[1]*py + m[2]*pz + m[9];
        const float ty = m[3]*px + m[4]*py + m[5]*pz + m[10];
        const float tz = m[6]*px + m[7]*py + m[8]*pz + m[11];
        const float fx = (tx + 1.0f) * 31.5f;   // 0.5*(64-1)
        const float fy = (ty + 1.0f) * 31.5f;
        const float fz = (tz + 1.0f) * 31.5f;
        const float x0f = floorf(fx), y0f = floorf(fy), z0f = floorf(fz);
        const float wx = fx - x0f, wy = fy - y0f, wz = fz - z0f;
        const int x0 = (int)x0f, y0 = (int)y0f, z0 = (int)z0f;
        const float* gb = grids + (size_t)g * (size_t)(2 * GR3);
        float f0 = 0.0f, f1 = 0.0f;
        #pragma unroll
        for (int dz = 0; dz < 2; ++dz) {
            #pragma unroll
            for (int dy = 0; dy < 2; ++dy) {
                #pragma unroll
                for (int dx = 0; dx < 2; ++dx) {
                    const int xi = x0 + dx, yi = y0 + dy, zi = z0 + dz;
                    const bool valid = ((unsigned)xi < (unsigned)GR) &
                                       ((unsigned)yi < (unsigned)GR) &
                                       ((unsigned)zi < (unsigned)GR);
                    const int xc = min(max(xi, 0), GR-1);
                    const int yc = min(max(yi, 0), GR-1);
                    const int zc = min(max(zi, 0), GR-1);
                    float w = (dx ? wx : 1.0f - wx) *
                              (dy ? wy : 1.0f - wy) *
                              (dz ? wz : 1.0f - wz);
                    w = valid ? w : 0.0f;
                    const int idx = (zc * GR + yc) * GR + xc;
                    f0 = fmaf(w, gb[idx], f0);
                    f1 = fmaf(w, gb[idx + GR3], f1);
                }
            }
        }
        feats[2*g + 0] = f0;
        feats[2*g + 1] = f1;
    }

    // Layer 0: 32 -> 64, ReLU.  Weight addresses are wave-uniform -> s_load.
    float h0[NNODES];
    #pragma unroll
    for (int j = 0; j < NNODES; ++j) h0[j] = b0[j];
    #pragma unroll 1
    for (int k = 0; k < DIN; ++k) {
        const float a = feats[k];
        const float* w = W0 + k * NNODES;
        #pragma unroll
        for (int j = 0; j < NNODES; ++j) h0[j] = fmaf(a, w[j], h0[j]);
    }
    #pragma unroll
    for (int j = 0; j < NNODES; ++j) h0[j] = fmaxf(h0[j], 0.0f);

    // Layer 1: 64 -> 64, ReLU fused into final dot.
    float h1[NNODES];
    #pragma unroll
    for (int j = 0; j < NNODES; ++j) h1[j] = b1[j];
    #pragma unroll 1
    for (int k = 0; k < NNODES; ++k) {
        const float a = h0[k];
        const float* w = W1 + k * NNODES;
        #pragma unroll
        for (int j = 0; j < NNODES; ++j) h1[j] = fmaf(a, w[j], h1[j]);
    }

    // Layer 2: 64 -> 1
    float y = b2[0];
    #pragma unroll 1
    for (int j = 0; j < NNODES; ++j) y = fmaf(fmaxf(h1[j], 0.0f), W2[j], y);

    out[n] = y;   // DATA_MAX - DATA_MIN = 1, DATA_MIN = 0
}

extern "C" void kernel_launch(void* const* d_in, const int* in_sizes, int n_in,
                              void* d_out, int out_size, void* d_ws, size_t ws_size,
                              hipStream_t stream) {
    const float* xs  = (const float*)d_in[0];
    const float* rot = (const float*)d_in[1];
    const float* scl = (const float*)d_in[2];
    const float* trn = (const float*)d_in[3];
    const float* gr  = (const float*)d_in[4];
    const float* W0  = (const float*)d_in[5];
    const float* b0  = (const float*)d_in[6];
    const float* W1  = (const float*)d_in[7];
    const float* b1  = (const float*)d_in[8];
    const float* W2  = (const float*)d_in[9];
    const float* b2  = (const float*)d_in[10];
    float* out = (float*)d_out;

    dim3 grid((NPTS + 255) / 256), block(256);
    hipLaunchKernelGGL(amgsrn_fused, grid, block, 0, stream,
                       xs, rot, scl, trn, gr, W0, b0, W1, b1, W2, b2, out);
}

// Round 2
// 383.547 us; speedup vs baseline: 2.0650x; 2.0650x over previous
//
#include <hip/hip_runtime.h>
#include <cstddef>
#include <cstdint>

constexpr int NPTS   = 524288;
constexpr int NG     = 16;
constexpr int GR     = 64;
constexpr int GR3    = GR * GR * GR;   // 262144
constexpr int DIN    = 32;
constexpr int NNODES = 64;
constexpr int NBINS  = 32768;          // 32^3 spatial cells, morton order

// workspace layout (bytes)
constexpr size_t GRIDS_BYTES = (size_t)NG * GR3 * 2 * 4;   // 32 MB interleaved
constexpr size_t WS_SORT     = GRIDS_BYTES;                 // NPTS * float4
constexpr size_t SORT_BYTES  = (size_t)NPTS * 16;           // 8 MB
constexpr size_t WS_BINS     = WS_SORT + SORT_BYTES;
constexpr size_t BINS_BYTES  = (size_t)NBINS * 4;
constexpr size_t WS_TOTAL    = WS_BINS + BINS_BYTES;

__device__ __forceinline__ unsigned part1by2(unsigned x) {
    x &= 0x3ff;
    x = (x | (x << 16)) & 0x030000FF;
    x = (x | (x <<  8)) & 0x0300F00F;
    x = (x | (x <<  4)) & 0x030C30C3;
    x = (x | (x <<  2)) & 0x09249249;
    return x;
}

__device__ __forceinline__ unsigned cell_of(float px, float py, float pz) {
    int cx = (int)((px + 1.0f) * 16.0f); cx = min(max(cx, 0), 31);
    int cy = (int)((py + 1.0f) * 16.0f); cy = min(max(cy, 0), 31);
    int cz = (int)((pz + 1.0f) * 16.0f); cz = min(max(cz, 0), 31);
    return part1by2((unsigned)cx) | (part1by2((unsigned)cy) << 1) | (part1by2((unsigned)cz) << 2);
}

// ---- grid repack: [g][c][z][y][x] -> [g][node][c] (float2 per node) ----
__global__ __launch_bounds__(256) void repack_grids(const float* __restrict__ grids,
                                                    float2* __restrict__ gout) {
    const int node = blockIdx.x * 256 + threadIdx.x;   // 0..GR3
    const int g = blockIdx.y;
    const float c0 = grids[((size_t)g * 2 + 0) * GR3 + node];
    const float c1 = grids[((size_t)g * 2 + 1) * GR3 + node];
    gout[(size_t)g * GR3 + node] = make_float2(c0, c1);
}

// ---- sort pass 1: histogram ----
__global__ __launch_bounds__(256) void hist_kernel(const float* __restrict__ xs,
                                                   unsigned* __restrict__ bins) {
    const int n = blockIdx.x * 256 + threadIdx.x;
    if (n >= NPTS) return;
    const unsigned key = cell_of(xs[n*3+0], xs[n*3+1], xs[n*3+2]);
    atomicAdd(&bins[key], 1u);
}

// ---- sort pass 2: exclusive scan of 32768 bins, single block ----
__global__ __launch_bounds__(1024) void scan_kernel(unsigned* __restrict__ bins) {
    __shared__ unsigned s[1024];
    const int t = threadIdx.x;
    unsigned loc[32];
    unsigned sum = 0;
    #pragma unroll
    for (int i = 0; i < 32; ++i) { loc[i] = bins[t * 32 + i]; sum += loc[i]; }
    s[t] = sum;
    __syncthreads();
    for (int off = 1; off < 1024; off <<= 1) {
        unsigned v = (t >= off) ? s[t - off] : 0u;
        __syncthreads();
        s[t] += v;
        __syncthreads();
    }
    unsigned run = s[t] - sum;   // exclusive base for this thread's 32 bins
    #pragma unroll
    for (int i = 0; i < 32; ++i) { bins[t * 32 + i] = run; run += loc[i]; }
}

// ---- sort pass 3: scatter points into morton order ----
__global__ __launch_bounds__(256) void scatter_kernel(const float* __restrict__ xs,
                                                      unsigned* __restrict__ bins,
                                                      float4* __restrict__ sorted) {
    const int n = blockIdx.x * 256 + threadIdx.x;
    if (n >= NPTS) return;
    const float px = xs[n*3+0], py = xs[n*3+1], pz = xs[n*3+2];
    const unsigned key = cell_of(px, py, pz);
    const unsigned pos = atomicAdd(&bins[key], 1u);
    sorted[pos] = make_float4(px, py, pz, __int_as_float(n));
}

// ---- main fused kernel (sorted points, interleaved grids) ----
__global__ __launch_bounds__(256) void amgsrn_main(
    const float4* __restrict__ sorted,
    const float*  __restrict__ rot,
    const float*  __restrict__ scl,
    const float*  __restrict__ trn,
    const float2* __restrict__ gridsI,
    const float*  __restrict__ W0,
    const float*  __restrict__ b0,
    const float*  __restrict__ W1,
    const float*  __restrict__ b1,
    const float*  __restrict__ W2,
    const float*  __restrict__ b2,
    float* __restrict__ out)
{
    __shared__ float sM[NG][12];
    const int tid = threadIdx.x;
    if (tid < NG) {
        const int g = tid;
        float qx = rot[g*4+0], qy = rot[g*4+1], qz = rot[g*4+2], qw = rot[g*4+3];
        const float inv = 1.0f / sqrtf(qx*qx + qy*qy + qz*qz + qw*qw);
        qx *= inv; qy *= inv; qz *= inv; qw *= inv;
        const float sx = expf(scl[g*3+0]);
        const float sy = expf(scl[g*3+1]);
        const float sz = expf(scl[g*3+2]);
        sM[g][0] = sx * (1.0f - 2.0f*(qy*qy + qz*qz));
        sM[g][1] = sx * (2.0f*(qx*qy - qz*qw));
        sM[g][2] = sx * (2.0f*(qx*qz + qy*qw));
        sM[g][3] = sy * (2.0f*(qx*qy + qz*qw));
        sM[g][4] = sy * (1.0f - 2.0f*(qx*qx + qz*qz));
        sM[g][5] = sy * (2.0f*(qy*qz - qx*qw));
        sM[g][6] = sz * (2.0f*(qx*qz - qy*qw));
        sM[g][7] = sz * (2.0f*(qy*qz + qx*qw));
        sM[g][8] = sz * (1.0f - 2.0f*(qx*qx + qy*qy));
        sM[g][9]  = trn[g*3+0];
        sM[g][10] = trn[g*3+1];
        sM[g][11] = trn[g*3+2];
    }
    __syncthreads();

    const int n = blockIdx.x * blockDim.x + tid;
    if (n >= NPTS) return;
    const float4 p = sorted[n];
    const float px = p.x, py = p.y, pz = p.z;
    const int orig = __float_as_int(p.w);

    float feats[DIN];

    #pragma unroll
    for (int g = 0; g < NG; ++g) {
        const float* m = sM[g];
        const float tx = m[0]*px + m[1]*py + m[2]*pz + m[9];
        const float ty = m[3]*px + m[4]*py + m[5]*pz + m[10];
        const float tz = m[6]*px + m[7]*py + m[8]*pz + m[11];
        const float fx = (tx + 1.0f) * 31.5f;
        const float fy = (ty + 1.0f) * 31.5f;
        const float fz = (tz + 1.0f) * 31.5f;
        const float x0f = floorf(fx), y0f = floorf(fy), z0f = floorf(fz);
        const float wx = fx - x0f, wy = fy - y0f, wz = fz - z0f;
        const int x0 = (int)x0f, y0 = (int)y0f, z0 = (int)z0f;
        const float2* gb = gridsI + (size_t)g * GR3;
        float f0 = 0.0f, f1 = 0.0f;
        #pragma unroll
        for (int dz = 0; dz < 2; ++dz) {
            const int zi = z0 + dz;
            const bool vz = ((unsigned)zi < (unsigned)GR);
            const int zc = min(max(zi, 0), GR-1);
            const float wwz = dz ? wz : 1.0f - wz;
            #pragma unroll
            for (int dy = 0; dy < 2; ++dy) {
                const int yi = y0 + dy;
                const bool vy = ((unsigned)yi < (unsigned)GR);
                const int yc = min(max(yi, 0), GR-1);
                const float wwy = dy ? wy : 1.0f - wy;
                const int row = (zc * GR + yc) * GR;
                #pragma unroll
                for (int dx = 0; dx < 2; ++dx) {
                    const int xi = x0 + dx;
                    const bool valid = vz & vy & ((unsigned)xi < (unsigned)GR);
                    const int xc = min(max(xi, 0), GR-1);
                    float w = (dx ? wx : 1.0f - wx) * wwy * wwz;
                    w = valid ? w : 0.0f;
                    const float2 v = gb[row + xc];
                    f0 = fmaf(w, v.x, f0);
                    f1 = fmaf(w, v.y, f1);
                }
            }
        }
        feats[2*g + 0] = f0;
        feats[2*g + 1] = f1;
    }

    float h0[NNODES];
    #pragma unroll
    for (int j = 0; j < NNODES; ++j) h0[j] = b0[j];
    #pragma unroll 1
    for (int k = 0; k < DIN; ++k) {
        const float a = feats[k];
        const float* w = W0 + k * NNODES;
        #pragma unroll
        for (int j = 0; j < NNODES; ++j) h0[j] = fmaf(a, w[j], h0[j]);
    }
    #pragma unroll
    for (int j = 0; j < NNODES; ++j) h0[j] = fmaxf(h0[j], 0.0f);

    float h1[NNODES];
    #pragma unroll
    for (int j = 0; j < NNODES; ++j) h1[j] = b1[j];
    #pragma unroll 1
    for (int k = 0; k < NNODES; ++k) {
        const float a = h0[k];
        const float* w = W1 + k * NNODES;
        #pragma unroll
        for (int j = 0; j < NNODES; ++j) h1[j] = fmaf(a, w[j], h1[j]);
    }

    float y = b2[0];
    #pragma unroll 1
    for (int j = 0; j < NNODES; ++j) y = fmaf(fmaxf(h1[j], 0.0f), W2[j], y);

    out[orig] = y;
}

// ---- round-1 fallback (unsorted, original layout) used if ws too small ----
__global__ __launch_bounds__(256) void amgsrn_fused_fallback(
    const float* __restrict__ xs,
    const float* __restrict__ rot,
    const float* __restrict__ scl,
    const float* __restrict__ trn,
    const float* __restrict__ grids,
    const float* __restrict__ W0,
    const float* __restrict__ b0,
    const float* __restrict__ W1,
    const float* __restrict__ b1,
    const float* __restrict__ W2,
    const float* __restrict__ b2,
    float* __restrict__ out)
{
    __shared__ float sM[NG][12];
    const int tid = threadIdx.x;
    if (tid < NG) {
        const int g = tid;
        float qx = rot[g*4+0], qy = rot[g*4+1], qz = rot[g*4+2], qw = rot[g*4+3];
        const float inv = 1.0f / sqrtf(qx*qx + qy*qy + qz*qz + qw*qw);
        qx *= inv; qy *= inv; qz *= inv; qw *= inv;
        const float sx = expf(scl[g*3+0]);
        const float sy = expf(scl[g*3+1]);
        const float sz = expf(scl[g*3+2]);
        sM[g][0] = sx * (1.0f - 2.0f*(qy*qy + qz*qz));
        sM[g][1] = sx * (2.0f*(qx*qy - qz*qw));
        sM[g][2] = sx * (2.0f*(qx*qz + qy*qw));
        sM[g][3] = sy * (2.0f*(qx*qy + qz*qw));
        sM[g][4] = sy * (1.0f - 2.0f*(qx*qx + qz*qz));
        sM[g][5] = sy * (2.0f*(qy*qz - qx*qw));
        sM[g][6] = sz * (2.0f*(qx*qz - qy*qw));
        sM[g][7] = sz * (2.0f*(qy*qz + qx*qw));
        sM[g][8] = sz * (1.0f - 2.0f*(qx*qx + qy*qy));
        sM[g][9]  = trn[g*3+0];
        sM[g][10] = trn[g*3+1];
        sM[g][11] = trn[g*3+2];
    }
    __syncthreads();

    const int n = blockIdx.x * blockDim.x + tid;
    if (n >= NPTS) return;
    const float px = xs[n*3+0];
    const float py = xs[n*3+1];
    const float pz = xs[n*3+2];

    float feats[DIN];
    #pragma unroll
    for (int g = 0; g < NG; ++g) {
        const float* m = sM[g];
        const float tx = m[0]*px + m[1]*py + m[2]*pz + m[9];
        const float ty = m[3]*px + m[4]*py + m[5]*pz + m[10];
        const float tz = m[6]*px + m[7]*py + m[8]*pz + m[11];
        const float fx = (tx + 1.0f) * 31.5f;
        const float fy = (ty + 1.0f) * 31.5f;
        const float fz = (tz + 1.0f) * 31.5f;
        const float x0f = floorf(fx), y0f = floorf(fy), z0f = floorf(fz);
        const float wx = fx - x0f, wy = fy - y0f, wz = fz - z0f;
        const int x0 = (int)x0f, y0 = (int)y0f, z0 = (int)z0f;
        const float* gb = grids + (size_t)g * (size_t)(2 * GR3);
        float f0 = 0.0f, f1 = 0.0f;
        #pragma unroll
        for (int dz = 0; dz < 2; ++dz) {
            #pragma unroll
            for (int dy = 0; dy < 2; ++dy) {
                #pragma unroll
                for (int dx = 0; dx < 2; ++dx) {
                    const int xi = x0 + dx, yi = y0 + dy, zi = z0 + dz;
                    const bool valid = ((unsigned)xi < (unsigned)GR) &
                                       ((unsigned)yi < (unsigned)GR) &
                                       ((unsigned)zi < (unsigned)GR);
                    const int xc = min(max(xi, 0), GR-1);
                    const int yc = min(max(yi, 0), GR-1);
                    const int zc = min(max(zi, 0), GR-1);
                    float w = (dx ? wx : 1.0f - wx) *
                              (dy ? wy : 1.0f - wy) *
                              (dz ? wz : 1.0f - wz);
                    w = valid ? w : 0.0f;
                    const int idx = (zc * GR + yc) * GR + xc;
                    f0 = fmaf(w, gb[idx], f0);
                    f1 = fmaf(w, gb[idx + GR3], f1);
                }
            }
        }
        feats[2*g + 0] = f0;
        feats[2*g + 1] = f1;
    }

    float h0[NNODES];
    #pragma unroll
    for (int j = 0; j < NNODES; ++j) h0[j] = b0[j];
    #pragma unroll 1
    for (int k = 0; k < DIN; ++k) {
        const float a = feats[k];
        const float* w = W0 + k * NNODES;
        #pragma unroll
        for (int j = 0; j < NNODES; ++j) h0[j] = fmaf(a, w[j], h0[j]);
    }
    #pragma unroll
    for (int j = 0; j < NNODES; ++j) h0[j] = fmaxf(h0[j], 0.0f);

    float h1[NNODES];
    #pragma unroll
    for (int j = 0; j < NNODES; ++j) h1[j] = b1[j];
    #pragma unroll 1
    for (int k = 0; k < NNODES; ++k) {
        const float a = h0[k];
        const float* w = W1 + k * NNODES;
        #pragma unroll
        for (int j = 0; j < NNODES; ++j) h1[j] = fmaf(a, w[j], h1[j]);
    }

    float y = b2[0];
    #pragma unroll 1
    for (int j = 0; j < NNODES; ++j) y = fmaf(fmaxf(h1[j], 0.0f), W2[j], y);

    out[n] = y;
}

extern "C" void kernel_launch(void* const* d_in, const int* in_sizes, int n_in,
                              void* d_out, int out_size, void* d_ws, size_t ws_size,
                              hipStream_t stream) {
    const float* xs  = (const float*)d_in[0];
    const float* rot = (const float*)d_in[1];
    const float* scl = (const float*)d_in[2];
    const float* trn = (const float*)d_in[3];
    const float* gr  = (const float*)d_in[4];
    const float* W0  = (const float*)d_in[5];
    const float* b0  = (const float*)d_in[6];
    const float* W1  = (const float*)d_in[7];
    const float* b1  = (const float*)d_in[8];
    const float* W2  = (const float*)d_in[9];
    const float* b2  = (const float*)d_in[10];
    float* out = (float*)d_out;

    if (ws_size < WS_TOTAL) {
        dim3 grid((NPTS + 255) / 256), block(256);
        hipLaunchKernelGGL(amgsrn_fused_fallback, grid, block, 0, stream,
                           xs, rot, scl, trn, gr, W0, b0, W1, b1, W2, b2, out);
        return;
    }

    char* ws = (char*)d_ws;
    float2*   gridsI = (float2*)(ws);
    float4*   sorted = (float4*)(ws + WS_SORT);
    unsigned* bins   = (unsigned*)(ws + WS_BINS);

    hipLaunchKernelGGL(repack_grids, dim3(GR3 / 256, NG), dim3(256), 0, stream,
                       gr, gridsI);
    hipMemsetAsync(bins, 0, BINS_BYTES, stream);
    hipLaunchKernelGGL(hist_kernel, dim3((NPTS + 255) / 256), dim3(256), 0, stream,
                       xs, bins);
    hipLaunchKernelGGL(scan_kernel, dim3(1), dim3(1024), 0, stream, bins);
    hipLaunchKernelGGL(scatter_kernel, dim3((NPTS + 255) / 256), dim3(256), 0, stream,
                       xs, bins, sorted);
    hipLaunchKernelGGL(amgsrn_main, dim3((NPTS + 255) / 256), dim3(256), 0, stream,
                       sorted, rot, scl, trn, gridsI, W0, b0, W1, b1, W2, b2, out);
}

// Round 3
// 370.773 us; speedup vs baseline: 2.1361x; 1.0345x over previous
//
#include <hip/hip_runtime.h>
#include <cstddef>
#include <cstdint>

constexpr int NPTS   = 524288;
constexpr int NG     = 16;
constexpr int GR     = 64;
constexpr int GR3    = GR * GR * GR;   // 262144
constexpr int DIN    = 32;
constexpr int NNODES = 64;
constexpr int NBINS  = 32768;          // 32^3 spatial cells, morton order

// workspace layout (bytes)
constexpr size_t GRIDS_BYTES = (size_t)NG * GR3 * 4;        // 16 MB bf16x2-packed
constexpr size_t WS_SORT     = GRIDS_BYTES;
constexpr size_t SORT_BYTES  = (size_t)NPTS * 16;           // 8 MB float4
constexpr size_t WS_KEYR     = WS_SORT + SORT_BYTES;
constexpr size_t KEYR_BYTES  = (size_t)NPTS * 4;            // 2 MB key|rank
constexpr size_t WS_BINS     = WS_KEYR + KEYR_BYTES;
constexpr size_t BINS_BYTES  = (size_t)NBINS * 4;
constexpr size_t WS_TOTAL    = WS_BINS + BINS_BYTES;

__device__ __forceinline__ unsigned part1by2(unsigned x) {
    x &= 0x3ff;
    x = (x | (x << 16)) & 0x030000FF;
    x = (x | (x <<  8)) & 0x0300F00F;
    x = (x | (x <<  4)) & 0x030C30C3;
    x = (x | (x <<  2)) & 0x09249249;
    return x;
}

__device__ __forceinline__ unsigned cell_of(float px, float py, float pz) {
    int cx = (int)((px + 1.0f) * 16.0f); cx = min(max(cx, 0), 31);
    int cy = (int)((py + 1.0f) * 16.0f); cy = min(max(cy, 0), 31);
    int cz = (int)((pz + 1.0f) * 16.0f); cz = min(max(cz, 0), 31);
    return part1by2((unsigned)cx) | (part1by2((unsigned)cy) << 1) | (part1by2((unsigned)cz) << 2);
}

__device__ __forceinline__ unsigned f32_to_bf16_rne(float f) {
    unsigned u = __float_as_uint(f);
    return (u + 0x7fffu + ((u >> 16) & 1u)) >> 16;
}

// ---- grid repack: [g][c][z][y][x] fp32 -> [g][node] uint(bf16 c1<<16 | c0) ----
__global__ __launch_bounds__(256) void repack_grids(const float* __restrict__ grids,
                                                    unsigned* __restrict__ gout) {
    const int node = blockIdx.x * 256 + threadIdx.x;
    const int g = blockIdx.y;
    const float c0 = grids[((size_t)g * 2 + 0) * GR3 + node];
    const float c1 = grids[((size_t)g * 2 + 1) * GR3 + node];
    gout[(size_t)g * GR3 + node] = f32_to_bf16_rne(c0) | (f32_to_bf16_rne(c1) << 16);
}

// ---- sort pass 1: histogram + per-point (key, rank) ----
__global__ __launch_bounds__(256) void hist_kernel(const float* __restrict__ xs,
                                                   unsigned* __restrict__ bins,
                                                   unsigned* __restrict__ keyrank) {
    const int n = blockIdx.x * 256 + threadIdx.x;
    if (n >= NPTS) return;
    const unsigned key = cell_of(xs[n*3+0], xs[n*3+1], xs[n*3+2]);
    const unsigned rank = atomicAdd(&bins[key], 1u);
    keyrank[n] = key | (rank << 15);
}

// ---- sort pass 2: exclusive scan of 32768 bins, single block ----
__global__ __launch_bounds__(1024) void scan_kernel(unsigned* __restrict__ bins) {
    __shared__ unsigned s[1024];
    const int t = threadIdx.x;
    unsigned loc[32];
    unsigned sum = 0;
    #pragma unroll
    for (int i = 0; i < 32; ++i) { loc[i] = bins[t * 32 + i]; sum += loc[i]; }
    s[t] = sum;
    __syncthreads();
    for (int off = 1; off < 1024; off <<= 1) {
        unsigned v = (t >= off) ? s[t - off] : 0u;
        __syncthreads();
        s[t] += v;
        __syncthreads();
    }
    unsigned run = s[t] - sum;
    #pragma unroll
    for (int i = 0; i < 32; ++i) { bins[t * 32 + i] = run; run += loc[i]; }
}

// ---- sort pass 3: plain scatter using scanned bases ----
__global__ __launch_bounds__(256) void scatter_kernel(const float* __restrict__ xs,
                                                      const unsigned* __restrict__ bins,
                                                      const unsigned* __restrict__ keyrank,
                                                      float4* __restrict__ sorted) {
    const int n = blockIdx.x * 256 + threadIdx.x;
    if (n >= NPTS) return;
    const unsigned kr = keyrank[n];
    const unsigned key = kr & 0x7fffu;
    const unsigned rank = kr >> 15;
    const unsigned pos = bins[key] + rank;
    sorted[pos] = make_float4(xs[n*3+0], xs[n*3+1], xs[n*3+2], __int_as_float(n));
}

// ---- main fused kernel (sorted points, bf16-packed grids) ----
__global__ __launch_bounds__(256) void amgsrn_main(
    const float4* __restrict__ sorted,
    const float*  __restrict__ rot,
    const float*  __restrict__ scl,
    const float*  __restrict__ trn,
    const unsigned* __restrict__ gridsI,
    const float*  __restrict__ W0,
    const float*  __restrict__ b0,
    const float*  __restrict__ W1,
    const float*  __restrict__ b1,
    const float*  __restrict__ W2,
    const float*  __restrict__ b2,
    float* __restrict__ out)
{
    __shared__ float sM[NG][12];
    const int tid = threadIdx.x;
    if (tid < NG) {
        const int g = tid;
        float qx = rot[g*4+0], qy = rot[g*4+1], qz = rot[g*4+2], qw = rot[g*4+3];
        const float inv = 1.0f / sqrtf(qx*qx + qy*qy + qz*qz + qw*qw);
        qx *= inv; qy *= inv; qz *= inv; qw *= inv;
        const float sx = expf(scl[g*3+0]);
        const float sy = expf(scl[g*3+1]);
        const float sz = expf(scl[g*3+2]);
        sM[g][0] = sx * (1.0f - 2.0f*(qy*qy + qz*qz));
        sM[g][1] = sx * (2.0f*(qx*qy - qz*qw));
        sM[g][2] = sx * (2.0f*(qx*qz + qy*qw));
        sM[g][3] = sy * (2.0f*(qx*qy + qz*qw));
        sM[g][4] = sy * (1.0f - 2.0f*(qx*qx + qz*qz));
        sM[g][5] = sy * (2.0f*(qy*qz - qx*qw));
        sM[g][6] = sz * (2.0f*(qx*qz - qy*qw));
        sM[g][7] = sz * (2.0f*(qy*qz + qx*qw));
        sM[g][8] = sz * (1.0f - 2.0f*(qx*qx + qy*qy));
        sM[g][9]  = trn[g*3+0];
        sM[g][10] = trn[g*3+1];
        sM[g][11] = trn[g*3+2];
    }
    __syncthreads();

    const int n = blockIdx.x * blockDim.x + tid;
    if (n >= NPTS) return;
    const float4 p = sorted[n];
    const float px = p.x, py = p.y, pz = p.z;
    const int orig = __float_as_int(p.w);

    float feats[DIN];

    #pragma unroll
    for (int g = 0; g < NG; ++g) {
        const float* m = sM[g];
        const float tx = m[0]*px + m[1]*py + m[2]*pz + m[9];
        const float ty = m[3]*px + m[4]*py + m[5]*pz + m[10];
        const float tz = m[6]*px + m[7]*py + m[8]*pz + m[11];
        const float fx = (tx + 1.0f) * 31.5f;
        const float fy = (ty + 1.0f) * 31.5f;
        const float fz = (tz + 1.0f) * 31.5f;
        const float x0f = floorf(fx), y0f = floorf(fy), z0f = floorf(fz);
        const float wx = fx - x0f, wy = fy - y0f, wz = fz - z0f;
        const int x0 = (int)x0f, y0 = (int)y0f, z0 = (int)z0f;
        const unsigned* gb = gridsI + (size_t)g * GR3;
        float f0 = 0.0f, f1 = 0.0f;
        #pragma unroll
        for (int dz = 0; dz < 2; ++dz) {
            const int zi = z0 + dz;
            const bool vz = ((unsigned)zi < (unsigned)GR);
            const int zc = min(max(zi, 0), GR-1);
            const float wwz = dz ? wz : 1.0f - wz;
            #pragma unroll
            for (int dy = 0; dy < 2; ++dy) {
                const int yi = y0 + dy;
                const bool vy = ((unsigned)yi < (unsigned)GR);
                const int yc = min(max(yi, 0), GR-1);
                const float wwy = dy ? wy : 1.0f - wy;
                const int row = (zc * GR + yc) * GR;
                #pragma unroll
                for (int dx = 0; dx < 2; ++dx) {
                    const int xi = x0 + dx;
                    const bool valid = vz & vy & ((unsigned)xi < (unsigned)GR);
                    const int xc = min(max(xi, 0), GR-1);
                    float w = (dx ? wx : 1.0f - wx) * wwy * wwz;
                    w = valid ? w : 0.0f;
                    const unsigned v = gb[row + xc];
                    f0 = fmaf(w, __uint_as_float(v << 16), f0);
                    f1 = fmaf(w, __uint_as_float(v & 0xffff0000u), f1);
                }
            }
        }
        feats[2*g + 0] = f0;
        feats[2*g + 1] = f1;
    }

    float h0[NNODES];
    #pragma unroll
    for (int j = 0; j < NNODES; ++j) h0[j] = b0[j];
    #pragma unroll 1
    for (int k = 0; k < DIN; ++k) {
        const float a = feats[k];
        const float* w = W0 + k * NNODES;
        #pragma unroll
        for (int j = 0; j < NNODES; ++j) h0[j] = fmaf(a, w[j], h0[j]);
    }
    #pragma unroll
    for (int j = 0; j < NNODES; ++j) h0[j] = fmaxf(h0[j], 0.0f);

    float h1[NNODES];
    #pragma unroll
    for (int j = 0; j < NNODES; ++j) h1[j] = b1[j];
    #pragma unroll 1
    for (int k = 0; k < NNODES; ++k) {
        const float a = h0[k];
        const float* w = W1 + k * NNODES;
        #pragma unroll
        for (int j = 0; j < NNODES; ++j) h1[j] = fmaf(a, w[j], h1[j]);
    }

    float y = b2[0];
    #pragma unroll 1
    for (int j = 0; j < NNODES; ++j) y = fmaf(fmaxf(h1[j], 0.0f), W2[j], y);

    out[orig] = y;
}

// ---- round-1 fallback (unsorted, original layout) used if ws too small ----
__global__ __launch_bounds__(256) void amgsrn_fused_fallback(
    const float* __restrict__ xs,
    const float* __restrict__ rot,
    const float* __restrict__ scl,
    const float* __restrict__ trn,
    const float* __restrict__ grids,
    const float* __restrict__ W0,
    const float* __restrict__ b0,
    const float* __restrict__ W1,
    const float* __restrict__ b1,
    const float* __restrict__ W2,
    const float* __restrict__ b2,
    float* __restrict__ out)
{
    __shared__ float sM[NG][12];
    const int tid = threadIdx.x;
    if (tid < NG) {
        const int g = tid;
        float qx = rot[g*4+0], qy = rot[g*4+1], qz = rot[g*4+2], qw = rot[g*4+3];
        const float inv = 1.0f / sqrtf(qx*qx + qy*qy + qz*qz + qw*qw);
        qx *= inv; qy *= inv; qz *= inv; qw *= inv;
        const float sx = expf(scl[g*3+0]);
        const float sy = expf(scl[g*3+1]);
        const float sz = expf(scl[g*3+2]);
        sM[g][0] = sx * (1.0f - 2.0f*(qy*qy + qz*qz));
        sM[g][1] = sx * (2.0f*(qx*qy - qz*qw));
        sM[g][2] = sx * (2.0f*(qx*qz + qy*qw));
        sM[g][3] = sy * (2.0f*(qx*qy + qz*qw));
        sM[g][4] = sy * (1.0f - 2.0f*(qx*qx + qz*qz));
        sM[g][5] = sy * (2.0f*(qy*qz - qx*qw));
        sM[g][6] = sz * (2.0f*(qx*qz - qy*qw));
        sM[g][7] = sz * (2.0f*(qy*qz + qx*qw));
        sM[g][8] = sz * (1.0f - 2.0f*(qx*qx + qy*qy));
        sM[g][9]  = trn[g*3+0];
        sM[g][10] = trn[g*3+1];
        sM[g][11] = trn[g*3+2];
    }
    __syncthreads();

    const int n = blockIdx.x * blockDim.x + tid;
    if (n >= NPTS) return;
    const float px = xs[n*3+0];
    const float py = xs[n*3+1];
    const float pz = xs[n*3+2];

    float feats[DIN];
    #pragma unroll
    for (int g = 0; g < NG; ++g) {
        const float* m = sM[g];
        const float tx = m[0]*px + m[1]*py + m[2]*pz + m[9];
        const float ty = m[3]*px + m[4]*py + m[5]*pz + m[10];
        const float tz = m[6]*px + m[7]*py + m[8]*pz + m[11];
        const float fx = (tx + 1.0f) * 31.5f;
        const float fy = (ty + 1.0f) * 31.5f;
        const float fz = (tz + 1.0f) * 31.5f;
        const float x0f = floorf(fx), y0f = floorf(fy), z0f = floorf(fz);
        const float wx = fx - x0f, wy = fy - y0f, wz = fz - z0f;
        const int x0 = (int)x0f, y0 = (int)y0f, z0 = (int)z0f;
        const float* gb = grids + (size_t)g * (size_t)(2 * GR3);
        float f0 = 0.0f, f1 = 0.0f;
        #pragma unroll
        for (int dz = 0; dz < 2; ++dz) {
            #pragma unroll
            for (int dy = 0; dy < 2; ++dy) {
                #pragma unroll
                for (int dx = 0; dx < 2; ++dx) {
                    const int xi = x0 + dx, yi = y0 + dy, zi = z0 + dz;
                    const bool valid = ((unsigned)xi < (unsigned)GR) &
                                       ((unsigned)yi < (unsigned)GR) &
                                       ((unsigned)zi < (unsigned)GR);
                    const int xc = min(max(xi, 0), GR-1);
                    const int yc = min(max(yi, 0), GR-1);
                    const int zc = min(max(zi, 0), GR-1);
                    float w = (dx ? wx : 1.0f - wx) *
                              (dy ? wy : 1.0f - wy) *
                              (dz ? wz : 1.0f - wz);
                    w = valid ? w : 0.0f;
                    const int idx = (zc * GR + yc) * GR + xc;
                    f0 = fmaf(w, gb[idx], f0);
                    f1 = fmaf(w, gb[idx + GR3], f1);
                }
            }
        }
        feats[2*g + 0] = f0;
        feats[2*g + 1] = f1;
    }

    float h0[NNODES];
    #pragma unroll
    for (int j = 0; j < NNODES; ++j) h0[j] = b0[j];
    #pragma unroll 1
    for (int k = 0; k < DIN; ++k) {
        const float a = feats[k];
        const float* w = W0 + k * NNODES;
        #pragma unroll
        for (int j = 0; j < NNODES; ++j) h0[j] = fmaf(a, w[j], h0[j]);
    }
    #pragma unroll
    for (int j = 0; j < NNODES; ++j) h0[j] = fmaxf(h0[j], 0.0f);

    float h1[NNODES];
    #pragma unroll
    for (int j = 0; j < NNODES; ++j) h1[j] = b1[j];
    #pragma unroll 1
    for (int k = 0; k < NNODES; ++k) {
        const float a = h0[k];
        const float* w = W1 + k * NNODES;
        #pragma unroll
        for (int j = 0; j < NNODES; ++j) h1[j] = fmaf(a, w[j], h1[j]);
    }

    float y = b2[0];
    #pragma unroll 1
    for (int j = 0; j < NNODES; ++j) y = fmaf(fmaxf(h1[j], 0.0f), W2[j], y);

    out[n] = y;
}

extern "C" void kernel_launch(void* const* d_in, const int* in_sizes, int n_in,
                              void* d_out, int out_size, void* d_ws, size_t ws_size,
                              hipStream_t stream) {
    const float* xs  = (const float*)d_in[0];
    const float* rot = (const float*)d_in[1];
    const float* scl = (const float*)d_in[2];
    const float* trn = (const float*)d_in[3];
    const float* gr  = (const float*)d_in[4];
    const float* W0  = (const float*)d_in[5];
    const float* b0  = (const float*)d_in[6];
    const float* W1  = (const float*)d_in[7];
    const float* b1  = (const float*)d_in[8];
    const float* W2  = (const float*)d_in[9];
    const float* b2  = (const float*)d_in[10];
    float* out = (float*)d_out;

    if (ws_size < WS_TOTAL) {
        dim3 grid((NPTS + 255) / 256), block(256);
        hipLaunchKernelGGL(amgsrn_fused_fallback, grid, block, 0, stream,
                           xs, rot, scl, trn, gr, W0, b0, W1, b1, W2, b2, out);
        return;
    }

    char* ws = (char*)d_ws;
    unsigned* gridsI  = (unsigned*)(ws);
    float4*   sorted  = (float4*)(ws + WS_SORT);
    unsigned* keyrank = (unsigned*)(ws + WS_KEYR);
    unsigned* bins    = (unsigned*)(ws + WS_BINS);

    hipLaunchKernelGGL(repack_grids, dim3(GR3 / 256, NG), dim3(256), 0, stream,
                       gr, gridsI);
    hipMemsetAsync(bins, 0, BINS_BYTES, stream);
    hipLaunchKernelGGL(hist_kernel, dim3((NPTS + 255) / 256), dim3(256), 0, stream,
                       xs, bins, keyrank);
    hipLaunchKernelGGL(scan_kernel, dim3(1), dim3(1024), 0, stream, bins);
    hipLaunchKernelGGL(scatter_kernel, dim3((NPTS + 255) / 256), dim3(256), 0, stream,
                       xs, bins, keyrank, sorted);
    hipLaunchKernelGGL(amgsrn_main, dim3((NPTS + 255) / 256), dim3(256), 0, stream,
                       sorted, rot, scl, trn, gridsI, W0, b0, W1, b1, W2, b2, out);
}

// Round 4
// 335.014 us; speedup vs baseline: 2.3641x; 1.1067x over previous
//
#include <hip/hip_runtime.h>
#include <cstddef>
#include <cstdint>

constexpr int NPTS   = 524288;
constexpr int NG     = 16;
constexpr int GR     = 64;
constexpr int GR3    = GR * GR * GR;   // 262144
constexpr int DIN    = 32;
constexpr int NNODES = 64;
constexpr int NBINS  = 32768;          // 32^3 spatial cells, morton order

// workspace layout (bytes)
constexpr size_t GRIDS_BYTES = (size_t)NG * GR3 * 8;        // 32 MB: x-pair replicated bf16x2 (uint2/node)
constexpr size_t WS_SORT     = GRIDS_BYTES;
constexpr size_t SORT_BYTES  = (size_t)NPTS * 16;           // 8 MB float4
constexpr size_t WS_KEYR     = WS_SORT + SORT_BYTES;
constexpr size_t KEYR_BYTES  = (size_t)NPTS * 4;            // 2 MB key|rank
constexpr size_t WS_BINS     = WS_KEYR + KEYR_BYTES;
constexpr size_t BINS_BYTES  = (size_t)NBINS * 4;
constexpr size_t WS_MATS     = WS_BINS + BINS_BYTES;
constexpr size_t MATS_BYTES  = (size_t)NG * 12 * 4;
constexpr size_t WS_TOTAL    = WS_MATS + MATS_BYTES;

__device__ __forceinline__ unsigned part1by2(unsigned x) {
    x &= 0x3ff;
    x = (x | (x << 16)) & 0x030000FF;
    x = (x | (x <<  8)) & 0x0300F00F;
    x = (x | (x <<  4)) & 0x030C30C3;
    x = (x | (x <<  2)) & 0x09249249;
    return x;
}

__device__ __forceinline__ unsigned cell_of(float px, float py, float pz) {
    int cx = (int)((px + 1.0f) * 16.0f); cx = min(max(cx, 0), 31);
    int cy = (int)((py + 1.0f) * 16.0f); cy = min(max(cy, 0), 31);
    int cz = (int)((pz + 1.0f) * 16.0f); cz = min(max(cz, 0), 31);
    return part1by2((unsigned)cx) | (part1by2((unsigned)cy) << 1) | (part1by2((unsigned)cz) << 2);
}

__device__ __forceinline__ unsigned f32_to_bf16_rne(float f) {
    unsigned u = __float_as_uint(f);
    return (u + 0x7fffu + ((u >> 16) & 1u)) >> 16;
}

// ---- transform matrices -> ws (16 x 12 floats), read by main via s_load ----
__global__ __launch_bounds__(64) void precompute_mats(const float* __restrict__ rot,
                                                      const float* __restrict__ scl,
                                                      const float* __restrict__ trn,
                                                      float* __restrict__ mats) {
    const int g = threadIdx.x;
    if (g >= NG) return;
    float qx = rot[g*4+0], qy = rot[g*4+1], qz = rot[g*4+2], qw = rot[g*4+3];
    const float inv = 1.0f / sqrtf(qx*qx + qy*qy + qz*qz + qw*qw);
    qx *= inv; qy *= inv; qz *= inv; qw *= inv;
    const float sx = expf(scl[g*3+0]);
    const float sy = expf(scl[g*3+1]);
    const float sz = expf(scl[g*3+2]);
    float* m = mats + g * 12;
    m[0] = sx * (1.0f - 2.0f*(qy*qy + qz*qz));
    m[1] = sx * (2.0f*(qx*qy - qz*qw));
    m[2] = sx * (2.0f*(qx*qz + qy*qw));
    m[3] = sy * (2.0f*(qx*qy + qz*qw));
    m[4] = sy * (1.0f - 2.0f*(qx*qx + qz*qz));
    m[5] = sy * (2.0f*(qy*qz - qx*qw));
    m[6] = sz * (2.0f*(qx*qz - qy*qw));
    m[7] = sz * (2.0f*(qy*qz + qx*qw));
    m[8] = sz * (1.0f - 2.0f*(qx*qx + qy*qy));
    m[9]  = trn[g*3+0];
    m[10] = trn[g*3+1];
    m[11] = trn[g*3+2];
}

// ---- grid repack: fp32 [g][c][z][y][x] -> uint2[g][node] = (bf16x2[x], bf16x2[x+1]) ----
__global__ __launch_bounds__(256) void repack_grids(const float* __restrict__ grids,
                                                    uint2* __restrict__ gout) {
    const int node = blockIdx.x * 256 + threadIdx.x;
    const int g = blockIdx.y;
    const int x = node & 63;
    const float* base = grids + (size_t)g * 2 * GR3;
    const int nodep = (x < 63) ? node + 1 : node;
    const float c0 = base[node],  c1 = base[GR3 + node];
    const float d0 = base[nodep], d1 = base[GR3 + nodep];
    gout[(size_t)g * GR3 + node] =
        make_uint2(f32_to_bf16_rne(c0) | (f32_to_bf16_rne(c1) << 16),
                   f32_to_bf16_rne(d0) | (f32_to_bf16_rne(d1) << 16));
}

// ---- sort pass 1: histogram + per-point (key, rank) ----
__global__ __launch_bounds__(256) void hist_kernel(const float* __restrict__ xs,
                                                   unsigned* __restrict__ bins,
                                                   unsigned* __restrict__ keyrank) {
    const int n = blockIdx.x * 256 + threadIdx.x;
    if (n >= NPTS) return;
    const unsigned key = cell_of(xs[n*3+0], xs[n*3+1], xs[n*3+2]);
    const unsigned rank = atomicAdd(&bins[key], 1u);
    keyrank[n] = key | (rank << 15);
}

// ---- sort pass 2: exclusive scan of 32768 bins, single block ----
__global__ __launch_bounds__(1024) void scan_kernel(unsigned* __restrict__ bins) {
    __shared__ unsigned s[1024];
    const int t = threadIdx.x;
    unsigned loc[32];
    unsigned sum = 0;
    #pragma unroll
    for (int i = 0; i < 32; ++i) { loc[i] = bins[t * 32 + i]; sum += loc[i]; }
    s[t] = sum;
    __syncthreads();
    for (int off = 1; off < 1024; off <<= 1) {
        unsigned v = (t >= off) ? s[t - off] : 0u;
        __syncthreads();
        s[t] += v;
        __syncthreads();
    }
    unsigned run = s[t] - sum;
    #pragma unroll
    for (int i = 0; i < 32; ++i) { bins[t * 32 + i] = run; run += loc[i]; }
}

// ---- sort pass 3: plain scatter using scanned bases ----
__global__ __launch_bounds__(256) void scatter_kernel(const float* __restrict__ xs,
                                                      const unsigned* __restrict__ bins,
                                                      const unsigned* __restrict__ keyrank,
                                                      float4* __restrict__ sorted) {
    const int n = blockIdx.x * 256 + threadIdx.x;
    if (n >= NPTS) return;
    const unsigned kr = keyrank[n];
    const unsigned key = kr & 0x7fffu;
    const unsigned rank = kr >> 15;
    const unsigned pos = bins[key] + rank;
    sorted[pos] = make_float4(xs[n*3+0], xs[n*3+1], xs[n*3+2], __int_as_float(n));
}

// ---- per-grid gather geometry ----
struct Geom {
    int i00, i01, i10, i11;           // uint2 element indices for (z,y) row combos
    float ax0, ax1, ay0, ay1, az0, az1;
    unsigned selhi, sello;
};

__device__ __forceinline__ Geom make_geom(const float* __restrict__ m,
                                          float px, float py, float pz, int g) {
    Geom G;
    const float tx = fmaf(m[0], px, fmaf(m[1], py, fmaf(m[2], pz, m[9])));
    const float ty = fmaf(m[3], px, fmaf(m[4], py, fmaf(m[5], pz, m[10])));
    const float tz = fmaf(m[6], px, fmaf(m[7], py, fmaf(m[8], pz, m[11])));
    const float fx = (tx + 1.0f) * 31.5f;
    const float fy = (ty + 1.0f) * 31.5f;
    const float fz = (tz + 1.0f) * 31.5f;
    const float x0f = floorf(fx), y0f = floorf(fy), z0f = floorf(fz);
    const float wx = fx - x0f, wy = fy - y0f, wz = fz - z0f;
    const int x0 = (int)x0f, y0 = (int)y0f, z0 = (int)z0f;
    G.ax0 = ((unsigned)x0       < 64u) ? (1.0f - wx) : 0.0f;
    G.ax1 = ((unsigned)(x0 + 1) < 64u) ? wx          : 0.0f;
    G.ay0 = ((unsigned)y0       < 64u) ? (1.0f - wy) : 0.0f;
    G.ay1 = ((unsigned)(y0 + 1) < 64u) ? wy          : 0.0f;
    G.az0 = ((unsigned)z0       < 64u) ? (1.0f - wz) : 0.0f;
    G.az1 = ((unsigned)(z0 + 1) < 64u) ? wz          : 0.0f;
    G.selhi = (x0 >= 63) ? 1u : 0u;   // corner0 value sits in pair.y (only when x0==63)
    G.sello = (x0 <= -1) ? 1u : 0u;   // corner1 value sits in pair.x (only when x0==-1)
    const int xb  = min(max(x0, 0), 62);
    const int yc0 = min(max(y0, 0), 63),     yc1 = min(max(y0 + 1, 0), 63);
    const int zc0 = min(max(z0, 0), 63),     zc1 = min(max(z0 + 1, 0), 63);
    const int b = (g << 18) + xb;
    G.i00 = b + (zc0 << 12) + (yc0 << 6);
    G.i01 = b + (zc0 << 12) + (yc1 << 6);
    G.i10 = b + (zc1 << 12) + (yc0 << 6);
    G.i11 = b + (zc1 << 12) + (yc1 << 6);
    return G;
}

__device__ __forceinline__ void acc_pair(float& f0, float& f1, const Geom& G,
                                         uint2 q, float wyz) {
    const unsigned v0 = G.selhi ? q.y : q.x;
    const unsigned v1 = G.sello ? q.x : q.y;
    float s0 = G.ax0 * __uint_as_float(v0 << 16);
    s0 = fmaf(G.ax1, __uint_as_float(v1 << 16), s0);
    f0 = fmaf(wyz, s0, f0);
    float s1 = G.ax0 * __uint_as_float(v0 & 0xffff0000u);
    s1 = fmaf(G.ax1, __uint_as_float(v1 & 0xffff0000u), s1);
    f1 = fmaf(wyz, s1, f1);
}

// ---- main fused kernel: sorted points, pair-replicated bf16 grid, spill-free MLP ----
__global__ __launch_bounds__(256, 4) void amgsrn_main(
    const float4* __restrict__ sorted,
    const uint2*  __restrict__ gridsP,
    const float*  __restrict__ mats,
    const float*  __restrict__ W0,
    const float*  __restrict__ b0,
    const float*  __restrict__ W1,
    const float*  __restrict__ b1,
    const float*  __restrict__ W2,
    const float*  __restrict__ b2,
    float* __restrict__ out)
{
    const int n = blockIdx.x * blockDim.x + threadIdx.x;
    if (n >= NPTS) return;
    const float4 p = sorted[n];
    const float px = p.x, py = p.y, pz = p.z;
    const int orig = __float_as_int(p.w);

    float feats[DIN];

    // software-pipelined gather: issue grid g+1's 4 loads before reducing grid g
    Geom G = make_geom(mats, px, py, pz, 0);
    uint2 q00 = gridsP[G.i00], q01 = gridsP[G.i01];
    uint2 q10 = gridsP[G.i10], q11 = gridsP[G.i11];
    #pragma unroll
    for (int g = 0; g < NG; ++g) {
        Geom Gn;
        uint2 n00, n01, n10, n11;
        if (g + 1 < NG) {
            Gn = make_geom(mats + (g + 1) * 12, px, py, pz, g + 1);
            n00 = gridsP[Gn.i00]; n01 = gridsP[Gn.i01];
            n10 = gridsP[Gn.i10]; n11 = gridsP[Gn.i11];
        }
        float f0 = 0.0f, f1 = 0.0f;
        acc_pair(f0, f1, G, q00, G.az0 * G.ay0);
        acc_pair(f0, f1, G, q01, G.az0 * G.ay1);
        acc_pair(f0, f1, G, q10, G.az1 * G.ay0);
        acc_pair(f0, f1, G, q11, G.az1 * G.ay1);
        feats[2*g + 0] = f0;
        feats[2*g + 1] = f1;
        if (g + 1 < NG) {
            G = Gn;
            q00 = n00; q01 = n01; q10 = n10; q11 = n11;
        }
    }

    // Layer 0: 32 -> 64, ReLU. k-outer, j-inner unrolled; W0 rows via s_load.
    float h0[NNODES];
    #pragma unroll
    for (int j = 0; j < NNODES; ++j) h0[j] = b0[j];
    #pragma unroll 1
    for (int k = 0; k < DIN; ++k) {
        const float a = feats[k];
        const float* w = W0 + k * NNODES;
        #pragma unroll
        for (int j = 0; j < NNODES; ++j) h0[j] = fmaf(a, w[j], h0[j]);
    }
    #pragma unroll
    for (int j = 0; j < NNODES; ++j) h0[j] = fmaxf(h0[j], 0.0f);

    // Layer 1 + layer 2, in two 32-wide halves (no h1[64] array -> no spills)
    float y = b2[0];
    {
        float h1[32];
        #pragma unroll
        for (int j = 0; j < 32; ++j) h1[j] = b1[j];
        #pragma unroll 1
        for (int k = 0; k < NNODES; ++k) {
            const float a = h0[k];
            const float* w = W1 + k * NNODES;
            #pragma unroll
            for (int j = 0; j < 32; ++j) h1[j] = fmaf(a, w[j], h1[j]);
        }
        #pragma unroll
        for (int j = 0; j < 32; ++j) y = fmaf(fmaxf(h1[j], 0.0f), W2[j], y);
    }
    {
        float h1[32];
        #pragma unroll
        for (int j = 0; j < 32; ++j) h1[j] = b1[32 + j];
        #pragma unroll 1
        for (int k = 0; k < NNODES; ++k) {
            const float a = h0[k];
            const float* w = W1 + k * NNODES + 32;
            #pragma unroll
            for (int j = 0; j < 32; ++j) h1[j] = fmaf(a, w[j], h1[j]);
        }
        #pragma unroll
        for (int j = 0; j < 32; ++j) y = fmaf(fmaxf(h1[j], 0.0f), W2[32 + j], y);
    }

    out[orig] = y;
}

// ---- fallback (unsorted, original layout) used if ws too small ----
__global__ __launch_bounds__(256, 4) void amgsrn_fused_fallback(
    const float* __restrict__ xs,
    const float* __restrict__ rot,
    const float* __restrict__ scl,
    const float* __restrict__ trn,
    const float* __restrict__ grids,
    const float* __restrict__ W0,
    const float* __restrict__ b0,
    const float* __restrict__ W1,
    const float* __restrict__ b1,
    const float* __restrict__ W2,
    const float* __restrict__ b2,
    float* __restrict__ out)
{
    __shared__ float sM[NG][12];
    const int tid = threadIdx.x;
    if (tid < NG) {
        const int g = tid;
        float qx = rot[g*4+0], qy = rot[g*4+1], qz = rot[g*4+2], qw = rot[g*4+3];
        const float inv = 1.0f / sqrtf(qx*qx + qy*qy + qz*qz + qw*qw);
        qx *= inv; qy *= inv; qz *= inv; qw *= inv;
        const float sx = expf(scl[g*3+0]);
        const float sy = expf(scl[g*3+1]);
        const float sz = expf(scl[g*3+2]);
        sM[g][0] = sx * (1.0f - 2.0f*(qy*qy + qz*qz));
        sM[g][1] = sx * (2.0f*(qx*qy - qz*qw));
        sM[g][2] = sx * (2.0f*(qx*qz + qy*qw));
        sM[g][3] = sy * (2.0f*(qx*qy + qz*qw));
        sM[g][4] = sy * (1.0f - 2.0f*(qx*qx + qz*qz));
        sM[g][5] = sy * (2.0f*(qy*qz - qx*qw));
        sM[g][6] = sz * (2.0f*(qx*qz - qy*qw));
        sM[g][7] = sz * (2.0f*(qy*qz + qx*qw));
        sM[g][8] = sz * (1.0f - 2.0f*(qx*qx + qy*qy));
        sM[g][9]  = trn[g*3+0];
        sM[g][10] = trn[g*3+1];
        sM[g][11] = trn[g*3+2];
    }
    __syncthreads();

    const int n = blockIdx.x * blockDim.x + tid;
    if (n >= NPTS) return;
    const float px = xs[n*3+0];
    const float py = xs[n*3+1];
    const float pz = xs[n*3+2];

    float feats[DIN];
    #pragma unroll
    for (int g = 0; g < NG; ++g) {
        const float* m = sM[g];
        const float tx = m[0]*px + m[1]*py + m[2]*pz + m[9];
        const float ty = m[3]*px + m[4]*py + m[5]*pz + m[10];
        const float tz = m[6]*px + m[7]*py + m[8]*pz + m[11];
        const float fx = (tx + 1.0f) * 31.5f;
        const float fy = (ty + 1.0f) * 31.5f;
        const float fz = (tz + 1.0f) * 31.5f;
        const float x0f = floorf(fx), y0f = floorf(fy), z0f = floorf(fz);
        const float wx = fx - x0f, wy = fy - y0f, wz = fz - z0f;
        const int x0 = (int)x0f, y0 = (int)y0f, z0 = (int)z0f;
        const float* gb = grids + (size_t)g * (size_t)(2 * GR3);
        float f0 = 0.0f, f1 = 0.0f;
        #pragma unroll
        for (int dz = 0; dz < 2; ++dz) {
            #pragma unroll
            for (int dy = 0; dy < 2; ++dy) {
                #pragma unroll
                for (int dx = 0; dx < 2; ++dx) {
                    const int xi = x0 + dx, yi = y0 + dy, zi = z0 + dz;
                    const bool valid = ((unsigned)xi < (unsigned)GR) &
                                       ((unsigned)yi < (unsigned)GR) &
                                       ((unsigned)zi < (unsigned)GR);
                    const int xc = min(max(xi, 0), GR-1);
                    const int yc = min(max(yi, 0), GR-1);
                    const int zc = min(max(zi, 0), GR-1);
                    float w = (dx ? wx : 1.0f - wx) *
                              (dy ? wy : 1.0f - wy) *
                              (dz ? wz : 1.0f - wz);
                    w = valid ? w : 0.0f;
                    const int idx = (zc * GR + yc) * GR + xc;
                    f0 = fmaf(w, gb[idx], f0);
                    f1 = fmaf(w, gb[idx + GR3], f1);
                }
            }
        }
        feats[2*g + 0] = f0;
        feats[2*g + 1] = f1;
    }

    float h0[NNODES];
    #pragma unroll
    for (int j = 0; j < NNODES; ++j) h0[j] = b0[j];
    #pragma unroll 1
    for (int k = 0; k < DIN; ++k) {
        const float a = feats[k];
        const float* w = W0 + k * NNODES;
        #pragma unroll
        for (int j = 0; j < NNODES; ++j) h0[j] = fmaf(a, w[j], h0[j]);
    }
    #pragma unroll
    for (int j = 0; j < NNODES; ++j) h0[j] = fmaxf(h0[j], 0.0f);

    float y = b2[0];
    {
        float h1[32];
        #pragma unroll
        for (int j = 0; j < 32; ++j) h1[j] = b1[j];
        #pragma unroll 1
        for (int k = 0; k < NNODES; ++k) {
            const float a = h0[k];
            const float* w = W1 + k * NNODES;
            #pragma unroll
            for (int j = 0; j < 32; ++j) h1[j] = fmaf(a, w[j], h1[j]);
        }
        #pragma unroll
        for (int j = 0; j < 32; ++j) y = fmaf(fmaxf(h1[j], 0.0f), W2[j], y);
    }
    {
        float h1[32];
        #pragma unroll
        for (int j = 0; j < 32; ++j) h1[j] = b1[32 + j];
        #pragma unroll 1
        for (int k = 0; k < NNODES; ++k) {
            const float a = h0[k];
            const float* w = W1 + k * NNODES + 32;
            #pragma unroll
            for (int j = 0; j < 32; ++j) h1[j] = fmaf(a, w[j], h1[j]);
        }
        #pragma unroll
        for (int j = 0; j < 32; ++j) y = fmaf(fmaxf(h1[j], 0.0f), W2[32 + j], y);
    }

    out[n] = y;
}

extern "C" void kernel_launch(void* const* d_in, const int* in_sizes, int n_in,
                              void* d_out, int out_size, void* d_ws, size_t ws_size,
                              hipStream_t stream) {
    const float* xs  = (const float*)d_in[0];
    const float* rot = (const float*)d_in[1];
    const float* scl = (const float*)d_in[2];
    const float* trn = (const float*)d_in[3];
    const float* gr  = (const float*)d_in[4];
    const float* W0  = (const float*)d_in[5];
    const float* b0  = (const float*)d_in[6];
    const float* W1  = (const float*)d_in[7];
    const float* b1  = (const float*)d_in[8];
    const float* W2  = (const float*)d_in[9];
    const float* b2  = (const float*)d_in[10];
    float* out = (float*)d_out;

    if (ws_size < WS_TOTAL) {
        dim3 grid((NPTS + 255) / 256), block(256);
        hipLaunchKernelGGL(amgsrn_fused_fallback, grid, block, 0, stream,
                           xs, rot, scl, trn, gr, W0, b0, W1, b1, W2, b2, out);
        return;
    }

    char* ws = (char*)d_ws;
    uint2*    gridsP  = (uint2*)(ws);
    float4*   sorted  = (float4*)(ws + WS_SORT);
    unsigned* keyrank = (unsigned*)(ws + WS_KEYR);
    unsigned* bins    = (unsigned*)(ws + WS_BINS);
    float*    mats    = (float*)(ws + WS_MATS);

    hipLaunchKernelGGL(precompute_mats, dim3(1), dim3(64), 0, stream,
                       rot, scl, trn, mats);
    hipLaunchKernelGGL(repack_grids, dim3(GR3 / 256, NG), dim3(256), 0, stream,
                       gr, gridsP);
    hipMemsetAsync(bins, 0, BINS_BYTES, stream);
    hipLaunchKernelGGL(hist_kernel, dim3((NPTS + 255) / 256), dim3(256), 0, stream,
                       xs, bins, keyrank);
    hipLaunchKernelGGL(scan_kernel, dim3(1), dim3(1024), 0, stream, bins);
    hipLaunchKernelGGL(scatter_kernel, dim3((NPTS + 255) / 256), dim3(256), 0, stream,
                       xs, bins, keyrank, sorted);
    hipLaunchKernelGGL(amgsrn_main, dim3((NPTS + 255) / 256), dim3(256), 0, stream,
                       sorted, gridsP, mats, W0, b0, W1, b1, W2, b2, out);
}

// Round 5
// 276.781 us; speedup vs baseline: 2.8615x; 1.2104x over previous
//
#include <hip/hip_runtime.h>
#include <cstddef>
#include <cstdint>

constexpr int NPTS   = 524288;
constexpr int NG     = 16;
constexpr int GR     = 64;
constexpr int GR3    = GR * GR * GR;   // 262144
constexpr int NNODES = 64;
constexpr int NBINS  = 32768;          // 32^3 spatial cells, morton order

// workspace layout (bytes)
constexpr size_t GRIDS_BYTES = (size_t)NG * GR3 * 8;        // 32 MB: x-pair replicated bf16x2 (uint2/node)
constexpr size_t WS_SORT     = GRIDS_BYTES;
constexpr size_t SORT_BYTES  = (size_t)NPTS * 16;           // 8 MB float4
constexpr size_t WS_KEYR     = WS_SORT + SORT_BYTES;
constexpr size_t KEYR_BYTES  = (size_t)NPTS * 4;            // 2 MB key|rank
constexpr size_t WS_BINS     = WS_KEYR + KEYR_BYTES;
constexpr size_t BINS_BYTES  = (size_t)NBINS * 4;
constexpr size_t WS_MATS     = WS_BINS + BINS_BYTES;
constexpr size_t MATS_BYTES  = (size_t)NG * 12 * 4;
constexpr size_t WS_TOTAL    = WS_MATS + MATS_BYTES;

__device__ __forceinline__ unsigned part1by2(unsigned x) {
    x &= 0x3ff;
    x = (x | (x << 16)) & 0x030000FF;
    x = (x | (x <<  8)) & 0x0300F00F;
    x = (x | (x <<  4)) & 0x030C30C3;
    x = (x | (x <<  2)) & 0x09249249;
    return x;
}

__device__ __forceinline__ unsigned cell_of(float px, float py, float pz) {
    int cx = (int)((px + 1.0f) * 16.0f); cx = min(max(cx, 0), 31);
    int cy = (int)((py + 1.0f) * 16.0f); cy = min(max(cy, 0), 31);
    int cz = (int)((pz + 1.0f) * 16.0f); cz = min(max(cz, 0), 31);
    return part1by2((unsigned)cx) | (part1by2((unsigned)cy) << 1) | (part1by2((unsigned)cz) << 2);
}

__device__ __forceinline__ unsigned f32_to_bf16_rne(float f) {
    unsigned u = __float_as_uint(f);
    return (u + 0x7fffu + ((u >> 16) & 1u)) >> 16;
}

// ---- transform matrices -> ws (16 x 12 floats) ----
__global__ __launch_bounds__(64) void precompute_mats(const float* __restrict__ rot,
                                                      const float* __restrict__ scl,
                                                      const float* __restrict__ trn,
                                                      float* __restrict__ mats) {
    const int g = threadIdx.x;
    if (g >= NG) return;
    float qx = rot[g*4+0], qy = rot[g*4+1], qz = rot[g*4+2], qw = rot[g*4+3];
    const float inv = 1.0f / sqrtf(qx*qx + qy*qy + qz*qz + qw*qw);
    qx *= inv; qy *= inv; qz *= inv; qw *= inv;
    const float sx = expf(scl[g*3+0]);
    const float sy = expf(scl[g*3+1]);
    const float sz = expf(scl[g*3+2]);
    float* m = mats + g * 12;
    m[0] = sx * (1.0f - 2.0f*(qy*qy + qz*qz));
    m[1] = sx * (2.0f*(qx*qy - qz*qw));
    m[2] = sx * (2.0f*(qx*qz + qy*qw));
    m[3] = sy * (2.0f*(qx*qy + qz*qw));
    m[4] = sy * (1.0f - 2.0f*(qx*qx + qz*qz));
    m[5] = sy * (2.0f*(qy*qz - qx*qw));
    m[6] = sz * (2.0f*(qx*qz - qy*qw));
    m[7] = sz * (2.0f*(qy*qz + qx*qw));
    m[8] = sz * (1.0f - 2.0f*(qx*qx + qy*qy));
    m[9]  = trn[g*3+0];
    m[10] = trn[g*3+1];
    m[11] = trn[g*3+2];
}

// ---- grid repack: fp32 [g][c][z][y][x] -> uint2[g][node] = (bf16x2[x], bf16x2[x+1]) ----
__global__ __launch_bounds__(256) void repack_grids(const float* __restrict__ grids,
                                                    uint2* __restrict__ gout) {
    const int node = blockIdx.x * 256 + threadIdx.x;
    const int g = blockIdx.y;
    const int x = node & 63;
    const float* base = grids + (size_t)g * 2 * GR3;
    const int nodep = (x < 63) ? node + 1 : node;
    const float c0 = base[node],  c1 = base[GR3 + node];
    const float d0 = base[nodep], d1 = base[GR3 + nodep];
    gout[(size_t)g * GR3 + node] =
        make_uint2(f32_to_bf16_rne(c0) | (f32_to_bf16_rne(c1) << 16),
                   f32_to_bf16_rne(d0) | (f32_to_bf16_rne(d1) << 16));
}

// ---- sort pass 1: histogram + per-point (key, rank) ----
__global__ __launch_bounds__(256) void hist_kernel(const float* __restrict__ xs,
                                                   unsigned* __restrict__ bins,
                                                   unsigned* __restrict__ keyrank) {
    const int n = blockIdx.x * 256 + threadIdx.x;
    if (n >= NPTS) return;
    const unsigned key = cell_of(xs[n*3+0], xs[n*3+1], xs[n*3+2]);
    const unsigned rank = atomicAdd(&bins[key], 1u);
    keyrank[n] = key | (rank << 15);
}

// ---- sort pass 2: exclusive scan of 32768 bins, single block ----
__global__ __launch_bounds__(1024) void scan_kernel(unsigned* __restrict__ bins) {
    __shared__ unsigned s[1024];
    const int t = threadIdx.x;
    unsigned loc[32];
    unsigned sum = 0;
    #pragma unroll
    for (int i = 0; i < 32; ++i) { loc[i] = bins[t * 32 + i]; sum += loc[i]; }
    s[t] = sum;
    __syncthreads();
    for (int off = 1; off < 1024; off <<= 1) {
        unsigned v = (t >= off) ? s[t - off] : 0u;
        __syncthreads();
        s[t] += v;
        __syncthreads();
    }
    unsigned run = s[t] - sum;
    #pragma unroll
    for (int i = 0; i < 32; ++i) { bins[t * 32 + i] = run; run += loc[i]; }
}

// ---- sort pass 3: plain scatter using scanned bases ----
__global__ __launch_bounds__(256) void scatter_kernel(const float* __restrict__ xs,
                                                      const unsigned* __restrict__ bins,
                                                      const unsigned* __restrict__ keyrank,
                                                      float4* __restrict__ sorted) {
    const int n = blockIdx.x * 256 + threadIdx.x;
    if (n >= NPTS) return;
    const unsigned kr = keyrank[n];
    const unsigned key = kr & 0x7fffu;
    const unsigned rank = kr >> 15;
    const unsigned pos = bins[key] + rank;
    sorted[pos] = make_float4(xs[n*3+0], xs[n*3+1], xs[n*3+2], __int_as_float(n));
}

// ---- per-grid gather geometry ----
struct Geom {
    int i00, i01, i10, i11;           // uint2 element indices for (z,y) row combos
    float ax0, ax1, ay0, ay1, az0, az1;
    unsigned selhi, sello;
};

__device__ __forceinline__ Geom make_geom(const float* __restrict__ m,
                                          float px, float py, float pz, int g) {
    Geom G;
    const float tx = fmaf(m[0], px, fmaf(m[1], py, fmaf(m[2], pz, m[9])));
    const float ty = fmaf(m[3], px, fmaf(m[4], py, fmaf(m[5], pz, m[10])));
    const float tz = fmaf(m[6], px, fmaf(m[7], py, fmaf(m[8], pz, m[11])));
    const float fx = (tx + 1.0f) * 31.5f;
    const float fy = (ty + 1.0f) * 31.5f;
    const float fz = (tz + 1.0f) * 31.5f;
    const float x0f = floorf(fx), y0f = floorf(fy), z0f = floorf(fz);
    const float wx = fx - x0f, wy = fy - y0f, wz = fz - z0f;
    const int x0 = (int)x0f, y0 = (int)y0f, z0 = (int)z0f;
    G.ax0 = ((unsigned)x0       < 64u) ? (1.0f - wx) : 0.0f;
    G.ax1 = ((unsigned)(x0 + 1) < 64u) ? wx          : 0.0f;
    G.ay0 = ((unsigned)y0       < 64u) ? (1.0f - wy) : 0.0f;
    G.ay1 = ((unsigned)(y0 + 1) < 64u) ? wy          : 0.0f;
    G.az0 = ((unsigned)z0       < 64u) ? (1.0f - wz) : 0.0f;
    G.az1 = ((unsigned)(z0 + 1) < 64u) ? wz          : 0.0f;
    G.selhi = (x0 >= 63) ? 1u : 0u;   // corner0 value sits in pair.y (only when x0==63)
    G.sello = (x0 <= -1) ? 1u : 0u;   // corner1 value sits in pair.x (only when x0==-1)
    const int xb  = min(max(x0, 0), 62);
    const int yc0 = min(max(y0, 0), 63),     yc1 = min(max(y0 + 1, 0), 63);
    const int zc0 = min(max(z0, 0), 63),     zc1 = min(max(z0 + 1, 0), 63);
    const int b = (g << 18) + xb;
    G.i00 = b + (zc0 << 12) + (yc0 << 6);
    G.i01 = b + (zc0 << 12) + (yc1 << 6);
    G.i10 = b + (zc1 << 12) + (yc0 << 6);
    G.i11 = b + (zc1 << 12) + (yc1 << 6);
    return G;
}

__device__ __forceinline__ void acc_pair(float& f0, float& f1, const Geom& G,
                                         uint2 q, float wyz) {
    const unsigned v0 = G.selhi ? q.y : q.x;
    const unsigned v1 = G.sello ? q.x : q.y;
    float s0 = G.ax0 * __uint_as_float(v0 << 16);
    s0 = fmaf(G.ax1, __uint_as_float(v1 << 16), s0);
    f0 = fmaf(wyz, s0, f0);
    float s1 = G.ax0 * __uint_as_float(v0 & 0xffff0000u);
    s1 = fmaf(G.ax1, __uint_as_float(v1 & 0xffff0000u), s1);
    f1 = fmaf(wyz, s1, f1);
}

// ---- main fused kernel: gather + layer0 folded, all-constant-index MLP ----
// __launch_bounds__(256,3): 168-VGPR ceiling so the ~115-reg live set cannot
// spill; actual usage still allows 4 waves/SIMD.
__global__ __launch_bounds__(256, 3) void amgsrn_main(
    const float4* __restrict__ sorted,
    const uint2*  __restrict__ gridsP,
    const float*  __restrict__ mats,
    const float*  __restrict__ W0,
    const float*  __restrict__ b0,
    const float*  __restrict__ W1,
    const float*  __restrict__ b1,
    const float*  __restrict__ W2,
    const float*  __restrict__ b2,
    float* __restrict__ out)
{
    const int n = blockIdx.x * blockDim.x + threadIdx.x;
    if (n >= NPTS) return;
    const float4 p = sorted[n];
    const float px = p.x, py = p.y, pz = p.z;
    const int orig = __float_as_int(p.w);

    // h0 accumulators live in registers for the whole gather (constant indices only)
    float h0[NNODES];
    #pragma unroll
    for (int j = 0; j < NNODES; ++j) h0[j] = b0[j];

    // software-pipelined gather; layer-0 FMAs for grid g hide grid g+1's loads
    Geom G = make_geom(mats, px, py, pz, 0);
    uint2 q00 = gridsP[G.i00], q01 = gridsP[G.i01];
    uint2 q10 = gridsP[G.i10], q11 = gridsP[G.i11];
    #pragma unroll
    for (int g = 0; g < NG; ++g) {
        Geom Gn;
        uint2 n00, n01, n10, n11;
        if (g + 1 < NG) {
            Gn = make_geom(mats + (g + 1) * 12, px, py, pz, g + 1);
            n00 = gridsP[Gn.i00]; n01 = gridsP[Gn.i01];
            n10 = gridsP[Gn.i10]; n11 = gridsP[Gn.i11];
        }
        float f0 = 0.0f, f1 = 0.0f;
        acc_pair(f0, f1, G, q00, G.az0 * G.ay0);
        acc_pair(f0, f1, G, q01, G.az0 * G.ay1);
        acc_pair(f0, f1, G, q10, G.az1 * G.ay0);
        acc_pair(f0, f1, G, q11, G.az1 * G.ay1);
        // layer 0 contribution of feats k=2g (f0) and k=2g+1 (f1)
        const float* w0a = W0 + (2*g    ) * NNODES;
        const float* w0b = W0 + (2*g + 1) * NNODES;
        #pragma unroll
        for (int j = 0; j < NNODES; ++j)
            h0[j] = fmaf(f1, w0b[j], fmaf(f0, w0a[j], h0[j]));
        if (g + 1 < NG) {
            G = Gn;
            q00 = n00; q01 = n01; q10 = n10; q11 = n11;
        }
    }
    #pragma unroll
    for (int j = 0; j < NNODES; ++j) h0[j] = fmaxf(h0[j], 0.0f);

    // Layer 1 + layer 2 in two 32-wide halves; k fully unrolled (const indices)
    float y = b2[0];
    #pragma unroll
    for (int half = 0; half < 2; ++half) {
        float h1[32];
        #pragma unroll
        for (int j = 0; j < 32; ++j) h1[j] = b1[half * 32 + j];
        #pragma unroll
        for (int k = 0; k < NNODES; ++k) {
            const float a = h0[k];
            const float* w = W1 + k * NNODES + half * 32;
            #pragma unroll
            for (int j = 0; j < 32; ++j) h1[j] = fmaf(a, w[j], h1[j]);
        }
        #pragma unroll
        for (int j = 0; j < 32; ++j) y = fmaf(fmaxf(h1[j], 0.0f), W2[half * 32 + j], y);
    }

    out[orig] = y;
}

// ---- fallback (unsorted, original layout) used if ws too small ----
__global__ __launch_bounds__(256, 3) void amgsrn_fused_fallback(
    const float* __restrict__ xs,
    const float* __restrict__ rot,
    const float* __restrict__ scl,
    const float* __restrict__ trn,
    const float* __restrict__ grids,
    const float* __restrict__ W0,
    const float* __restrict__ b0,
    const float* __restrict__ W1,
    const float* __restrict__ b1,
    const float* __restrict__ W2,
    const float* __restrict__ b2,
    float* __restrict__ out)
{
    __shared__ float sM[NG][12];
    const int tid = threadIdx.x;
    if (tid < NG) {
        const int g = tid;
        float qx = rot[g*4+0], qy = rot[g*4+1], qz = rot[g*4+2], qw = rot[g*4+3];
        const float inv = 1.0f / sqrtf(qx*qx + qy*qy + qz*qz + qw*qw);
        qx *= inv; qy *= inv; qz *= inv; qw *= inv;
        const float sx = expf(scl[g*3+0]);
        const float sy = expf(scl[g*3+1]);
        const float sz = expf(scl[g*3+2]);
        sM[g][0] = sx * (1.0f - 2.0f*(qy*qy + qz*qz));
        sM[g][1] = sx * (2.0f*(qx*qy - qz*qw));
        sM[g][2] = sx * (2.0f*(qx*qz + qy*qw));
        sM[g][3] = sy * (2.0f*(qx*qy + qz*qw));
        sM[g][4] = sy * (1.0f - 2.0f*(qx*qx + qz*qz));
        sM[g][5] = sy * (2.0f*(qy*qz - qx*qw));
        sM[g][6] = sz * (2.0f*(qx*qz - qy*qw));
        sM[g][7] = sz * (2.0f*(qy*qz + qx*qw));
        sM[g][8] = sz * (1.0f - 2.0f*(qx*qx + qy*qy));
        sM[g][9]  = trn[g*3+0];
        sM[g][10] = trn[g*3+1];
        sM[g][11] = trn[g*3+2];
    }
    __syncthreads();

    const int n = blockIdx.x * blockDim.x + tid;
    if (n >= NPTS) return;
    const float px = xs[n*3+0];
    const float py = xs[n*3+1];
    const float pz = xs[n*3+2];

    float h0[NNODES];
    #pragma unroll
    for (int j = 0; j < NNODES; ++j) h0[j] = b0[j];

    #pragma unroll
    for (int g = 0; g < NG; ++g) {
        const float* m = sM[g];
        const float tx = m[0]*px + m[1]*py + m[2]*pz + m[9];
        const float ty = m[3]*px + m[4]*py + m[5]*pz + m[10];
        const float tz = m[6]*px + m[7]*py + m[8]*pz + m[11];
        const float fx = (tx + 1.0f) * 31.5f;
        const float fy = (ty + 1.0f) * 31.5f;
        const float fz = (tz + 1.0f) * 31.5f;
        const float x0f = floorf(fx), y0f = floorf(fy), z0f = floorf(fz);
        const float wx = fx - x0f, wy = fy - y0f, wz = fz - z0f;
        const int x0 = (int)x0f, y0 = (int)y0f, z0 = (int)z0f;
        const float* gb = grids + (size_t)g * (size_t)(2 * GR3);
        float f0 = 0.0f, f1 = 0.0f;
        #pragma unroll
        for (int dz = 0; dz < 2; ++dz) {
            #pragma unroll
            for (int dy = 0; dy < 2; ++dy) {
                #pragma unroll
                for (int dx = 0; dx < 2; ++dx) {
                    const int xi = x0 + dx, yi = y0 + dy, zi = z0 + dz;
                    const bool valid = ((unsigned)xi < (unsigned)GR) &
                                       ((unsigned)yi < (unsigned)GR) &
                                       ((unsigned)zi < (unsigned)GR);
                    const int xc = min(max(xi, 0), GR-1);
                    const int yc = min(max(yi, 0), GR-1);
                    const int zc = min(max(zi, 0), GR-1);
                    float w = (dx ? wx : 1.0f - wx) *
                              (dy ? wy : 1.0f - wy) *
                              (dz ? wz : 1.0f - wz);
                    w = valid ? w : 0.0f;
                    const int idx = (zc * GR + yc) * GR + xc;
                    f0 = fmaf(w, gb[idx], f0);
                    f1 = fmaf(w, gb[idx + GR3], f1);
                }
            }
        }
        const float* w0a = W0 + (2*g    ) * NNODES;
        const float* w0b = W0 + (2*g + 1) * NNODES;
        #pragma unroll
        for (int j = 0; j < NNODES; ++j)
            h0[j] = fmaf(f1, w0b[j], fmaf(f0, w0a[j], h0[j]));
    }
    #pragma unroll
    for (int j = 0; j < NNODES; ++j) h0[j] = fmaxf(h0[j], 0.0f);

    float y = b2[0];
    #pragma unroll
    for (int half = 0; half < 2; ++half) {
        float h1[32];
        #pragma unroll
        for (int j = 0; j < 32; ++j) h1[j] = b1[half * 32 + j];
        #pragma unroll
        for (int k = 0; k < NNODES; ++k) {
            const float a = h0[k];
            const float* w = W1 + k * NNODES + half * 32;
            #pragma unroll
            for (int j = 0; j < 32; ++j) h1[j] = fmaf(a, w[j], h1[j]);
        }
        #pragma unroll
        for (int j = 0; j < 32; ++j) y = fmaf(fmaxf(h1[j], 0.0f), W2[half * 32 + j], y);
    }

    out[n] = y;
}

extern "C" void kernel_launch(void* const* d_in, const int* in_sizes, int n_in,
                              void* d_out, int out_size, void* d_ws, size_t ws_size,
                              hipStream_t stream) {
    const float* xs  = (const float*)d_in[0];
    const float* rot = (const float*)d_in[1];
    const float* scl = (const float*)d_in[2];
    const float* trn = (const float*)d_in[3];
    const float* gr  = (const float*)d_in[4];
    const float* W0  = (const float*)d_in[5];
    const float* b0  = (const float*)d_in[6];
    const float* W1  = (const float*)d_in[7];
    const float* b1  = (const float*)d_in[8];
    const float* W2  = (const float*)d_in[9];
    const float* b2  = (const float*)d_in[10];
    float* out = (float*)d_out;

    if (ws_size < WS_TOTAL) {
        dim3 grid((NPTS + 255) / 256), block(256);
        hipLaunchKernelGGL(amgsrn_fused_fallback, grid, block, 0, stream,
                           xs, rot, scl, trn, gr, W0, b0, W1, b1, W2, b2, out);
        return;
    }

    char* ws = (char*)d_ws;
    uint2*    gridsP  = (uint2*)(ws);
    float4*   sorted  = (float4*)(ws + WS_SORT);
    unsigned* keyrank = (unsigned*)(ws + WS_KEYR);
    unsigned* bins    = (unsigned*)(ws + WS_BINS);
    float*    mats    = (float*)(ws + WS_MATS);

    hipLaunchKernelGGL(precompute_mats, dim3(1), dim3(64), 0, stream,
                       rot, scl, trn, mats);
    hipLaunchKernelGGL(repack_grids, dim3(GR3 / 256, NG), dim3(256), 0, stream,
                       gr, gridsP);
    hipMemsetAsync(bins, 0, BINS_BYTES, stream);
    hipLaunchKernelGGL(hist_kernel, dim3((NPTS + 255) / 256), dim3(256), 0, stream,
                       xs, bins, keyrank);
    hipLaunchKernelGGL(scan_kernel, dim3(1), dim3(1024), 0, stream, bins);
    hipLaunchKernelGGL(scatter_kernel, dim3((NPTS + 255) / 256), dim3(256), 0, stream,
                       xs, bins, keyrank, sorted);
    hipLaunchKernelGGL(amgsrn_main, dim3((NPTS + 255) / 256), dim3(256), 0, stream,
                       sorted, gridsP, mats, W0, b0, W1, b1, W2, b2, out);
}

// Round 7
// 197.294 us; speedup vs baseline: 4.0144x; 1.4029x over previous
//
#include <hip/hip_runtime.h>
#include <cstddef>
#include <cstdint>

constexpr int NPTS   = 524288;
constexpr int NG     = 16;
constexpr int GR     = 64;
constexpr int GR3    = GR * GR * GR;   // 262144
constexpr int NNODES = 64;
constexpr int NBINS  = 32768;          // 32^3 spatial cells, morton order

// workspace layout (bytes)
constexpr size_t GRIDS_BYTES = (size_t)NG * GR3 * 8;        // 32 MB: x-pair replicated bf16x2 (uint2/node)
constexpr size_t WS_SORT     = GRIDS_BYTES;
constexpr size_t SORT_BYTES  = (size_t)NPTS * 16;           // 8 MB float4
constexpr size_t WS_KEYR     = WS_SORT + SORT_BYTES;
constexpr size_t KEYR_BYTES  = (size_t)NPTS * 4;            // 2 MB key|rank
constexpr size_t WS_BINS     = WS_KEYR + KEYR_BYTES;
constexpr size_t BINS_BYTES  = (size_t)NBINS * 4;
constexpr size_t WS_MATS     = WS_BINS + BINS_BYTES;
constexpr size_t MATS_BYTES  = 1024;                        // 16*12 floats, padded
constexpr size_t WS_WPACK    = WS_MATS + MATS_BYTES;
constexpr size_t WPACK_BYTES = (size_t)(256 + 512) * 16;    // B0: 256 uint4, B1: 512 uint4
constexpr size_t WS_TOTAL    = WS_WPACK + WPACK_BYTES;

typedef _Float16 half8 __attribute__((ext_vector_type(8)));
typedef float    floatx4 __attribute__((ext_vector_type(4)));

__device__ __forceinline__ unsigned part1by2(unsigned x) {
    x &= 0x3ff;
    x = (x | (x << 16)) & 0x030000FF;
    x = (x | (x <<  8)) & 0x0300F00F;
    x = (x | (x <<  4)) & 0x030C30C3;
    x = (x | (x <<  2)) & 0x09249249;
    return x;
}

__device__ __forceinline__ unsigned cell_of(float px, float py, float pz) {
    int cx = (int)((px + 1.0f) * 16.0f); cx = min(max(cx, 0), 31);
    int cy = (int)((py + 1.0f) * 16.0f); cy = min(max(cy, 0), 31);
    int cz = (int)((pz + 1.0f) * 16.0f); cz = min(max(cz, 0), 31);
    return part1by2((unsigned)cx) | (part1by2((unsigned)cy) << 1) | (part1by2((unsigned)cz) << 2);
}

__device__ __forceinline__ unsigned f32_to_bf16_rne(float f) {
    unsigned u = __float_as_uint(f);
    return (u + 0x7fffu + ((u >> 16) & 1u)) >> 16;
}

// pack two floats to fp16x2 (RNE)
__device__ __forceinline__ unsigned pack_h2(float a, float b) {
    unsigned short ua = __builtin_bit_cast(unsigned short, (_Float16)a);
    unsigned short ub = __builtin_bit_cast(unsigned short, (_Float16)b);
    return (unsigned)ua | ((unsigned)ub << 16);
}

// ---- transform matrices -> ws (16 x 12 floats) ----
__global__ __launch_bounds__(64) void precompute_mats(const float* __restrict__ rot,
                                                      const float* __restrict__ scl,
                                                      const float* __restrict__ trn,
                                                      float* __restrict__ mats) {
    const int g = threadIdx.x;
    if (g >= NG) return;
    float qx = rot[g*4+0], qy = rot[g*4+1], qz = rot[g*4+2], qw = rot[g*4+3];
    const float inv = 1.0f / sqrtf(qx*qx + qy*qy + qz*qz + qw*qw);
    qx *= inv; qy *= inv; qz *= inv; qw *= inv;
    const float sx = expf(scl[g*3+0]);
    const float sy = expf(scl[g*3+1]);
    const float sz = expf(scl[g*3+2]);
    float* m = mats + g * 12;
    m[0] = sx * (1.0f - 2.0f*(qy*qy + qz*qz));
    m[1] = sx * (2.0f*(qx*qy - qz*qw));
    m[2] = sx * (2.0f*(qx*qz + qy*qw));
    m[3] = sy * (2.0f*(qx*qy + qz*qw));
    m[4] = sy * (1.0f - 2.0f*(qx*qx + qz*qz));
    m[5] = sy * (2.0f*(qy*qz - qx*qw));
    m[6] = sz * (2.0f*(qx*qz - qy*qw));
    m[7] = sz * (2.0f*(qy*qz + qx*qw));
    m[8] = sz * (1.0f - 2.0f*(qx*qx + qy*qy));
    m[9]  = trn[g*3+0];
    m[10] = trn[g*3+1];
    m[11] = trn[g*3+2];
}

// ---- pack W0/W1 into MFMA B-fragment order (fp16) ----
// B-frag convention (m97 gemm_bt): lane (c=lane&15, q=lane>>4) holds
// B[k=q*8+j][n=c] for j=0..7, 16B contiguous per lane.
__global__ __launch_bounds__(256) void pack_weights(const float* __restrict__ W0,
                                                    const float* __restrict__ W1,
                                                    uint4* __restrict__ wpack) {
    const int tid = threadIdx.x;
    const int t = tid >> 6;          // ntile
    const int lane = tid & 63;
    const int q = lane >> 4, c = lane & 15;
    const int n = t * 16 + c;
    // B0: k = q*8+j (0..31)
    {
        unsigned u[4];
        #pragma unroll
        for (int jj = 0; jj < 4; ++jj) {
            const int k0 = q * 8 + 2 * jj;
            u[jj] = pack_h2(W0[k0 * NNODES + n], W0[(k0 + 1) * NNODES + n]);
        }
        wpack[t * 64 + lane] = make_uint4(u[0], u[1], u[2], u[3]);
    }
    // B1: ks in {0,1}, k = ks*32 + q*8 + j
    #pragma unroll
    for (int ks = 0; ks < 2; ++ks) {
        unsigned u[4];
        #pragma unroll
        for (int jj = 0; jj < 4; ++jj) {
            const int k0 = ks * 32 + q * 8 + 2 * jj;
            u[jj] = pack_h2(W1[k0 * NNODES + n], W1[(k0 + 1) * NNODES + n]);
        }
        wpack[256 + (ks * 4 + t) * 64 + lane] = make_uint4(u[0], u[1], u[2], u[3]);
    }
}

// ---- grid repack: fp32 [g][c][z][y][x] -> uint2[g][node] = (bf16x2[x], bf16x2[x+1]) ----
__global__ __launch_bounds__(256) void repack_grids(const float* __restrict__ grids,
                                                    uint2* __restrict__ gout) {
    const int node = blockIdx.x * 256 + threadIdx.x;
    const int g = blockIdx.y;
    const int x = node & 63;
    const float* base = grids + (size_t)g * 2 * GR3;
    const int nodep = (x < 63) ? node + 1 : node;
    const float c0 = base[node],  c1 = base[GR3 + node];
    const float d0 = base[nodep], d1 = base[GR3 + nodep];
    gout[(size_t)g * GR3 + node] =
        make_uint2(f32_to_bf16_rne(c0) | (f32_to_bf16_rne(c1) << 16),
                   f32_to_bf16_rne(d0) | (f32_to_bf16_rne(d1) << 16));
}

// ---- sort pass 1: histogram + per-point (key, rank) ----
__global__ __launch_bounds__(256) void hist_kernel(const float* __restrict__ xs,
                                                   unsigned* __restrict__ bins,
                                                   unsigned* __restrict__ keyrank) {
    const int n = blockIdx.x * 256 + threadIdx.x;
    if (n >= NPTS) return;
    const unsigned key = cell_of(xs[n*3+0], xs[n*3+1], xs[n*3+2]);
    const unsigned rank = atomicAdd(&bins[key], 1u);
    keyrank[n] = key | (rank << 15);
}

// ---- sort pass 2: exclusive scan of 32768 bins, single block ----
__global__ __launch_bounds__(1024) void scan_kernel(unsigned* __restrict__ bins) {
    __shared__ unsigned s[1024];
    const int t = threadIdx.x;
    unsigned loc[32];
    unsigned sum = 0;
    #pragma unroll
    for (int i = 0; i < 32; ++i) { loc[i] = bins[t * 32 + i]; sum += loc[i]; }
    s[t] = sum;
    __syncthreads();
    for (int off = 1; off < 1024; off <<= 1) {
        unsigned v = (t >= off) ? s[t - off] : 0u;
        __syncthreads();
        s[t] += v;
        __syncthreads();
    }
    unsigned run = s[t] - sum;
    #pragma unroll
    for (int i = 0; i < 32; ++i) { bins[t * 32 + i] = run; run += loc[i]; }
}

// ---- sort pass 3: plain scatter using scanned bases ----
__global__ __launch_bounds__(256) void scatter_kernel(const float* __restrict__ xs,
                                                      const unsigned* __restrict__ bins,
                                                      const unsigned* __restrict__ keyrank,
                                                      float4* __restrict__ sorted) {
    const int n = blockIdx.x * 256 + threadIdx.x;
    if (n >= NPTS) return;
    const unsigned kr = keyrank[n];
    const unsigned key = kr & 0x7fffu;
    const unsigned rank = kr >> 15;
    const unsigned pos = bins[key] + rank;
    sorted[pos] = make_float4(xs[n*3+0], xs[n*3+1], xs[n*3+2], __int_as_float(n));
}

// ---- per-grid gather geometry ----
struct Geom {
    int i00, i01, i10, i11;
    float ax0, ax1, ay0, ay1, az0, az1;
    unsigned selhi, sello;
};

__device__ __forceinline__ Geom make_geom(const float* __restrict__ m,
                                          float px, float py, float pz, int g) {
    Geom G;
    const float tx = fmaf(m[0], px, fmaf(m[1], py, fmaf(m[2], pz, m[9])));
    const float ty = fmaf(m[3], px, fmaf(m[4], py, fmaf(m[5], pz, m[10])));
    const float tz = fmaf(m[6], px, fmaf(m[7], py, fmaf(m[8], pz, m[11])));
    const float fx = (tx + 1.0f) * 31.5f;
    const float fy = (ty + 1.0f) * 31.5f;
    const float fz = (tz + 1.0f) * 31.5f;
    const float x0f = floorf(fx), y0f = floorf(fy), z0f = floorf(fz);
    const float wx = fx - x0f, wy = fy - y0f, wz = fz - z0f;
    const int x0 = (int)x0f, y0 = (int)y0f, z0 = (int)z0f;
    G.ax0 = ((unsigned)x0       < 64u) ? (1.0f - wx) : 0.0f;
    G.ax1 = ((unsigned)(x0 + 1) < 64u) ? wx          : 0.0f;
    G.ay0 = ((unsigned)y0       < 64u) ? (1.0f - wy) : 0.0f;
    G.ay1 = ((unsigned)(y0 + 1) < 64u) ? wy          : 0.0f;
    G.az0 = ((unsigned)z0       < 64u) ? (1.0f - wz) : 0.0f;
    G.az1 = ((unsigned)(z0 + 1) < 64u) ? wz          : 0.0f;
    G.selhi = (x0 >= 63) ? 1u : 0u;
    G.sello = (x0 <= -1) ? 1u : 0u;
    const int xb  = min(max(x0, 0), 62);
    const int yc0 = min(max(y0, 0), 63),     yc1 = min(max(y0 + 1, 0), 63);
    const int zc0 = min(max(z0, 0), 63),     zc1 = min(max(z0 + 1, 0), 63);
    const int b = (g << 18) + xb;
    G.i00 = b + (zc0 << 12) + (yc0 << 6);
    G.i01 = b + (zc0 << 12) + (yc1 << 6);
    G.i10 = b + (zc1 << 12) + (yc0 << 6);
    G.i11 = b + (zc1 << 12) + (yc1 << 6);
    return G;
}

__device__ __forceinline__ void acc_pair(float& f0, float& f1, const Geom& G,
                                         uint2 q, float wyz) {
    const unsigned v0 = G.selhi ? q.y : q.x;
    const unsigned v1 = G.sello ? q.x : q.y;
    float s0 = G.ax0 * __uint_as_float(v0 << 16);
    s0 = fmaf(G.ax1, __uint_as_float(v1 << 16), s0);
    f0 = fmaf(wyz, s0, f0);
    float s1 = G.ax0 * __uint_as_float(v0 & 0xffff0000u);
    s1 = fmaf(G.ax1, __uint_as_float(v1 & 0xffff0000u), s1);
    f1 = fmaf(wyz, s1, f1);
}

// ---- main fused kernel: gather (VALU) + MLP layers 0/1 on MFMA ----
// LDS stages are type-punned (uint4/half8/unsigned/ushort views of one arena):
// hipcc has strict-aliasing TBAA, so every stage boundary gets a
// __syncthreads() memory fence to forbid cross-stage reordering. Control
// flow is block-uniform throughout, so the barriers are safe.
constexpr int ARENA_H = 64 * 66;       // ushorts per wave arena (h0 [node][pt], stride 66)
constexpr int FSTRIDE = 40;            // feats row stride in halves (bank-conflict pad)

__global__ __launch_bounds__(256, 3) void amgsrn_main(
    const float4* __restrict__ sorted,
    const uint2*  __restrict__ gridsP,
    const float*  __restrict__ mats,
    const uint4*  __restrict__ wpack,
    const float*  __restrict__ b0,
    const float*  __restrict__ b1,
    const float*  __restrict__ W2,
    const float*  __restrict__ b2,
    float* __restrict__ out)
{
    __shared__ unsigned short sh[4 * ARENA_H];
    __shared__ float yS[256];

    const int tid  = threadIdx.x;
    const int lane = tid & 63;
    const int wv   = tid >> 6;
    const int c    = lane & 15;
    const int q    = lane >> 4;
    unsigned short* wa = sh + wv * ARENA_H;

    const int n = blockIdx.x * 256 + tid;          // NPTS % 256 == 0: always valid
    const float4 p = sorted[n];
    const float px = p.x, py = p.y, pz = p.z;
    const int orig = __float_as_int(p.w);

    // ---- gather: 16 grids -> fp16-packed feature pairs (registers, const-indexed)
    unsigned pk[NG];
    Geom G = make_geom(mats, px, py, pz, 0);
    uint2 q00 = gridsP[G.i00], q01 = gridsP[G.i01];
    uint2 q10 = gridsP[G.i10], q11 = gridsP[G.i11];
    #pragma unroll
    for (int g = 0; g < NG; ++g) {
        Geom Gn;
        uint2 n00, n01, n10, n11;
        if (g + 1 < NG) {
            Gn = make_geom(mats + (g + 1) * 12, px, py, pz, g + 1);
            n00 = gridsP[Gn.i00]; n01 = gridsP[Gn.i01];
            n10 = gridsP[Gn.i10]; n11 = gridsP[Gn.i11];
        }
        float f0 = 0.0f, f1 = 0.0f;
        acc_pair(f0, f1, G, q00, G.az0 * G.ay0);
        acc_pair(f0, f1, G, q01, G.az0 * G.ay1);
        acc_pair(f0, f1, G, q10, G.az1 * G.ay0);
        acc_pair(f0, f1, G, q11, G.az1 * G.ay1);
        pk[g] = pack_h2(f0, f1);                   // feat 2g (low), 2g+1 (high)
        if (g + 1 < NG) {
            G = Gn;
            q00 = n00; q01 = n01; q10 = n10; q11 = n11;
        }
    }

    // ---- stage feats to LDS [pt][32 halves], row stride FSTRIDE halves
    {
        uint4* dst = (uint4*)(wa + lane * FSTRIDE); // 80B-aligned -> 16B-aligned
        dst[0] = make_uint4(pk[0],  pk[1],  pk[2],  pk[3]);
        dst[1] = make_uint4(pk[4],  pk[5],  pk[6],  pk[7]);
        dst[2] = make_uint4(pk[8],  pk[9],  pk[10], pk[11]);
        dst[3] = make_uint4(pk[12], pk[13], pk[14], pk[15]);
    }
    __syncthreads();   // fence: feats writes (uint4) -> A0 reads (half8)

    // ---- A0 fragments: A[m=pt][k=feat], lane holds pt=m*16+c, k=q*8..q*8+7
    half8 a0[4];
    #pragma unroll
    for (int m = 0; m < 4; ++m)
        a0[m] = *(const half8*)(wa + (m * 16 + c) * FSTRIDE + q * 8);

    // ---- B fragments + bias/W2 lane constants
    half8 b0f[4], b1f[2][4];
    #pragma unroll
    for (int t = 0; t < 4; ++t)
        b0f[t] = __builtin_bit_cast(half8, wpack[t * 64 + lane]);
    #pragma unroll
    for (int ks = 0; ks < 2; ++ks)
        #pragma unroll
        for (int t = 0; t < 4; ++t)
            b1f[ks][t] = __builtin_bit_cast(half8, wpack[256 + (ks * 4 + t) * 64 + lane]);
    float b0v[4], b1v[4], w2v[4];
    #pragma unroll
    for (int t = 0; t < 4; ++t) {
        b0v[t] = b0[t * 16 + c];
        b1v[t] = b1[t * 16 + c];
        w2v[t] = W2[t * 16 + c];
    }
    const float b2s = b2[0];

    __syncthreads();   // fence: A0 reads complete before layer-0 stores reuse the arena

    // ---- layer 0: 16 MFMA; D[pt][node]: col=node(c), rows=pt (q*4+reg)
    // store relu(h0) as fp16 to LDS [node][pt] (stride 66 halves)
    #pragma unroll
    for (int t = 0; t < 4; ++t) {
        #pragma unroll
        for (int m = 0; m < 4; ++m) {
            floatx4 acc = {b0v[t], b0v[t], b0v[t], b0v[t]};
            acc = __builtin_amdgcn_mfma_f32_16x16x32_f16(a0[m], b0f[t], acc, 0, 0, 0);
            const int node = t * 16 + c;
            const int pt   = m * 16 + q * 4;
            unsigned* w32 = (unsigned*)(wa + node * 66 + pt);  // 4B-aligned
            w32[0] = pack_h2(fmaxf(acc[0], 0.0f), fmaxf(acc[1], 0.0f));
            w32[1] = pack_h2(fmaxf(acc[2], 0.0f), fmaxf(acc[3], 0.0f));
        }
    }
    __syncthreads();   // fence: h0 writes (unsigned) -> A1 reads (ushort)

    // ---- A1 fragments: A[m=pt][k=node], k = ks*32 + q*8 + j
    half8 a1[4][2];
    #pragma unroll
    for (int m = 0; m < 4; ++m) {
        #pragma unroll
        for (int ks = 0; ks < 2; ++ks) {
            unsigned u[4];
            #pragma unroll
            for (int jj = 0; jj < 4; ++jj) {
                const int k0 = ks * 32 + q * 8 + 2 * jj;
                const unsigned lo = wa[k0 * 66 + m * 16 + c];
                const unsigned hi = wa[(k0 + 1) * 66 + m * 16 + c];
                u[jj] = lo | (hi << 16);
            }
            a1[m][ks] = __builtin_bit_cast(half8, make_uint4(u[0], u[1], u[2], u[3]));
        }
    }

    // ---- layer 1 (32 MFMA) + layer 2 folded into epilogue on D-registers
    float p4[4][4];
    #pragma unroll
    for (int m = 0; m < 4; ++m)
        #pragma unroll
        for (int r = 0; r < 4; ++r) p4[m][r] = 0.0f;

    #pragma unroll
    for (int t = 0; t < 4; ++t) {
        #pragma unroll
        for (int m = 0; m < 4; ++m) {
            floatx4 acc = {b1v[t], b1v[t], b1v[t], b1v[t]};
            acc = __builtin_amdgcn_mfma_f32_16x16x32_f16(a1[m][0], b1f[0][t], acc, 0, 0, 0);
            acc = __builtin_amdgcn_mfma_f32_16x16x32_f16(a1[m][1], b1f[1][t], acc, 0, 0, 0);
            #pragma unroll
            for (int r = 0; r < 4; ++r)
                p4[m][r] = fmaf(fmaxf(acc[r], 0.0f), w2v[t], p4[m][r]);
        }
    }

    // reduce partials across the 16 cols (lanes differing in low 4 bits)
    #pragma unroll
    for (int m = 0; m < 4; ++m)
        #pragma unroll
        for (int r = 0; r < 4; ++r) {
            float v = p4[m][r];
            v += __shfl_xor(v, 1, 64);
            v += __shfl_xor(v, 2, 64);
            v += __shfl_xor(v, 4, 64);
            v += __shfl_xor(v, 8, 64);
            p4[m][r] = v + b2s;
        }

    // lane c==0 of each quad publishes its 16 point results
    if (c == 0) {
        #pragma unroll
        for (int m = 0; m < 4; ++m)
            #pragma unroll
            for (int r = 0; r < 4; ++r)
                yS[wv * 64 + m * 16 + q * 4 + r] = p4[m][r];
    }
    __syncthreads();   // fence: yS writes -> yS reads
    out[orig] = yS[tid];
}

// ---- fallback (unsorted, original layout, pure fp32) used if ws too small ----
__global__ __launch_bounds__(256, 3) void amgsrn_fused_fallback(
    const float* __restrict__ xs,
    const float* __restrict__ rot,
    const float* __restrict__ scl,
    const float* __restrict__ trn,
    const float* __restrict__ grids,
    const float* __restrict__ W0,
    const float* __restrict__ b0,
    const float* __restrict__ W1,
    const float* __restrict__ b1,
    const float* __restrict__ W2,
    const float* __restrict__ b2,
    float* __restrict__ out)
{
    __shared__ float sM[NG][12];
    const int tid = threadIdx.x;
    if (tid < NG) {
        const int g = tid;
        float qx = rot[g*4+0], qy = rot[g*4+1], qz = rot[g*4+2], qw = rot[g*4+3];
        const float inv = 1.0f / sqrtf(qx*qx + qy*qy + qz*qz + qw*qw);
        qx *= inv; qy *= inv; qz *= inv; qw *= inv;
        const float sx = expf(scl[g*3+0]);
        const float sy = expf(scl[g*3+1]);
        const float sz = expf(scl[g*3+2]);
        sM[g][0] = sx * (1.0f - 2.0f*(qy*qy + qz*qz));
        sM[g][1] = sx * (2.0f*(qx*qy - qz*qw));
        sM[g][2] = sx * (2.0f*(qx*qz + qy*qw));
        sM[g][3] = sy * (2.0f*(qx*qy + qz*qw));
        sM[g][4] = sy * (1.0f - 2.0f*(qx*qx + qz*qz));
        sM[g][5] = sy * (2.0f*(qy*qz - qx*qw));
        sM[g][6] = sz * (2.0f*(qx*qz - qy*qw));
        sM[g][7] = sz * (2.0f*(qy*qz + qx*qw));
        sM[g][8] = sz * (1.0f - 2.0f*(qx*qx + qy*qy));
        sM[g][9]  = trn[g*3+0];
        sM[g][10] = trn[g*3+1];
        sM[g][11] = trn[g*3+2];
    }
    __syncthreads();

    const int n = blockIdx.x * blockDim.x + tid;
    if (n >= NPTS) return;
    const float px = xs[n*3+0];
    const float py = xs[n*3+1];
    const float pz = xs[n*3+2];

    float h0[NNODES];
    #pragma unroll
    for (int j = 0; j < NNODES; ++j) h0[j] = b0[j];

    #pragma unroll
    for (int g = 0; g < NG; ++g) {
        const float* m = sM[g];
        const float tx = m[0]*px + m[1]*py + m[2]*pz + m[9];
        const float ty = m[3]*px + m[4]*py + m[5]*pz + m[10];
        const float tz = m[6]*px + m[7]*py + m[8]*pz + m[11];
        const float fx = (tx + 1.0f) * 31.5f;
        const float fy = (ty + 1.0f) * 31.5f;
        const float fz = (tz + 1.0f) * 31.5f;
        const float x0f = floorf(fx), y0f = floorf(fy), z0f = floorf(fz);
        const float wx = fx - x0f, wy = fy - y0f, wz = fz - z0f;
        const int x0 = (int)x0f, y0 = (int)y0f, z0 = (int)z0f;
        const float* gb = grids + (size_t)g * (size_t)(2 * GR3);
        float f0 = 0.0f, f1 = 0.0f;
        #pragma unroll
        for (int dz = 0; dz < 2; ++dz) {
            #pragma unroll
            for (int dy = 0; dy < 2; ++dy) {
                #pragma unroll
                for (int dx = 0; dx < 2; ++dx) {
                    const int xi = x0 + dx, yi = y0 + dy, zi = z0 + dz;
                    const bool valid = ((unsigned)xi < (unsigned)GR) &
                                       ((unsigned)yi < (unsigned)GR) &
                                       ((unsigned)zi < (unsigned)GR);
                    const int xc = min(max(xi, 0), GR-1);
                    const int yc = min(max(yi, 0), GR-1);
                    const int zc = min(max(zi, 0), GR-1);
                    float w = (dx ? wx : 1.0f - wx) *
                              (dy ? wy : 1.0f - wy) *
                              (dz ? wz : 1.0f - wz);
                    w = valid ? w : 0.0f;
                    const int idx = (zc * GR + yc) * GR + xc;
                    f0 = fmaf(w, gb[idx], f0);
                    f1 = fmaf(w, gb[idx + GR3], f1);
                }
            }
        }
        const float* w0a = W0 + (2*g    ) * NNODES;
        const float* w0b = W0 + (2*g + 1) * NNODES;
        #pragma unroll
        for (int j = 0; j < NNODES; ++j)
            h0[j] = fmaf(f1, w0b[j], fmaf(f0, w0a[j], h0[j]));
    }
    #pragma unroll
    for (int j = 0; j < NNODES; ++j) h0[j] = fmaxf(h0[j], 0.0f);

    float y = b2[0];
    #pragma unroll
    for (int half = 0; half < 2; ++half) {
        float h1[32];
        #pragma unroll
        for (int j = 0; j < 32; ++j) h1[j] = b1[half * 32 + j];
        #pragma unroll
        for (int k = 0; k < NNODES; ++k) {
            const float a = h0[k];
            const float* w = W1 + k * NNODES + half * 32;
            #pragma unroll
            for (int j = 0; j < 32; ++j) h1[j] = fmaf(a, w[j], h1[j]);
        }
        #pragma unroll
        for (int j = 0; j < 32; ++j) y = fmaf(fmaxf(h1[j], 0.0f), W2[half * 32 + j], y);
    }

    out[n] = y;
}

extern "C" void kernel_launch(void* const* d_in, const int* in_sizes, int n_in,
                              void* d_out, int out_size, void* d_ws, size_t ws_size,
                              hipStream_t stream) {
    const float* xs  = (const float*)d_in[0];
    const float* rot = (const float*)d_in[1];
    const float* scl = (const float*)d_in[2];
    const float* trn = (const float*)d_in[3];
    const float* gr  = (const float*)d_in[4];
    const float* W0  = (const float*)d_in[5];
    const float* b0  = (const float*)d_in[6];
    const float* W1  = (const float*)d_in[7];
    const float* b1  = (const float*)d_in[8];
    const float* W2  = (const float*)d_in[9];
    const float* b2  = (const float*)d_in[10];
    float* out = (float*)d_out;

    if (ws_size < WS_TOTAL) {
        dim3 grid((NPTS + 255) / 256), block(256);
        hipLaunchKernelGGL(amgsrn_fused_fallback, grid, block, 0, stream,
                           xs, rot, scl, trn, gr, W0, b0, W1, b1, W2, b2, out);
        return;
    }

    char* ws = (char*)d_ws;
    uint2*    gridsP  = (uint2*)(ws);
    float4*   sorted  = (float4*)(ws + WS_SORT);
    unsigned* keyrank = (unsigned*)(ws + WS_KEYR);
    unsigned* bins    = (unsigned*)(ws + WS_BINS);
    float*    mats    = (float*)(ws + WS_MATS);
    uint4*    wpack   = (uint4*)(ws + WS_WPACK);

    hipLaunchKernelGGL(precompute_mats, dim3(1), dim3(64), 0, stream,
                       rot, scl, trn, mats);
    hipLaunchKernelGGL(pack_weights, dim3(1), dim3(256), 0, stream,
                       W0, W1, wpack);
    hipLaunchKernelGGL(repack_grids, dim3(GR3 / 256, NG), dim3(256), 0, stream,
                       gr, gridsP);
    hipMemsetAsync(bins, 0, BINS_BYTES, stream);
    hipLaunchKernelGGL(hist_kernel, dim3((NPTS + 255) / 256), dim3(256), 0, stream,
                       xs, bins, keyrank);
    hipLaunchKernelGGL(scan_kernel, dim3(1), dim3(1024), 0, stream, bins);
    hipLaunchKernelGGL(scatter_kernel, dim3((NPTS + 255) / 256), dim3(256), 0, stream,
                       xs, bins, keyrank, sorted);
    hipLaunchKernelGGL(amgsrn_main, dim3(NPTS / 256), dim3(256), 0, stream,
                       sorted, gridsP, mats, wpack, b0, b1, W2, b2, out);
}

// Round 8
// 196.822 us; speedup vs baseline: 4.0241x; 1.0024x over previous
//
#include <hip/hip_runtime.h>
#include <cstddef>
#include <cstdint>

constexpr int NPTS   = 524288;
constexpr int NG     = 16;
constexpr int GR     = 64;
constexpr int GR3    = GR * GR * GR;   // 262144
constexpr int NNODES = 64;
constexpr int NBINS  = 32768;          // 32^3 spatial cells, morton order

// workspace layout (bytes)
constexpr size_t GRIDS_BYTES = (size_t)NG * GR3 * 8;        // 32 MB: x-pair replicated bf16x2 (uint2/node)
constexpr size_t WS_SORT     = GRIDS_BYTES;
constexpr size_t SORT_BYTES  = (size_t)NPTS * 16;           // 8 MB float4
constexpr size_t WS_KEYR     = WS_SORT + SORT_BYTES;
constexpr size_t KEYR_BYTES  = (size_t)NPTS * 4;            // 2 MB key|rank
constexpr size_t WS_BINS     = WS_KEYR + KEYR_BYTES;
constexpr size_t BINS_BYTES  = (size_t)NBINS * 4;
constexpr size_t WS_MATS     = WS_BINS + BINS_BYTES;
constexpr size_t MATS_BYTES  = 1024;                        // 16*12 floats, padded
constexpr size_t WS_WPACK    = WS_MATS + MATS_BYTES;
constexpr size_t WPACK_BYTES = (size_t)(256 + 512) * 16;    // B0: 256 uint4, B1: 512 uint4
constexpr size_t WS_TOTAL    = WS_WPACK + WPACK_BYTES;

// prep kernel block-role ranges
constexpr int PREP_REPACK = 4096;      // 4096 blocks * 256 thr * 4 nodes = NG*GR3
constexpr int PREP_HIST   = 2048;      // 2048 blocks * 256 thr = NPTS

typedef _Float16 half8 __attribute__((ext_vector_type(8)));
typedef float    floatx4 __attribute__((ext_vector_type(4)));

__device__ __forceinline__ unsigned part1by2(unsigned x) {
    x &= 0x3ff;
    x = (x | (x << 16)) & 0x030000FF;
    x = (x | (x <<  8)) & 0x0300F00F;
    x = (x | (x <<  4)) & 0x030C30C3;
    x = (x | (x <<  2)) & 0x09249249;
    return x;
}

__device__ __forceinline__ unsigned cell_of(float px, float py, float pz) {
    int cx = (int)((px + 1.0f) * 16.0f); cx = min(max(cx, 0), 31);
    int cy = (int)((py + 1.0f) * 16.0f); cy = min(max(cy, 0), 31);
    int cz = (int)((pz + 1.0f) * 16.0f); cz = min(max(cz, 0), 31);
    return part1by2((unsigned)cx) | (part1by2((unsigned)cy) << 1) | (part1by2((unsigned)cz) << 2);
}

__device__ __forceinline__ unsigned f32_to_bf16_rne(float f) {
    unsigned u = __float_as_uint(f);
    return (u + 0x7fffu + ((u >> 16) & 1u)) >> 16;
}

// pack two floats to fp16x2 (RNE)
__device__ __forceinline__ unsigned pack_h2(float a, float b) {
    unsigned short ua = __builtin_bit_cast(unsigned short, (_Float16)a);
    unsigned short ub = __builtin_bit_cast(unsigned short, (_Float16)b);
    return (unsigned)ua | ((unsigned)ub << 16);
}

// ---- fused prep: repack grids | hist | mats | pack weights (independent) ----
__global__ __launch_bounds__(256) void prep_kernel(
    const float* __restrict__ grids, uint2* __restrict__ gout,
    const float* __restrict__ xs, unsigned* __restrict__ bins,
    unsigned* __restrict__ keyrank,
    const float* __restrict__ rot, const float* __restrict__ scl,
    const float* __restrict__ trn, float* __restrict__ mats,
    const float* __restrict__ W0, const float* __restrict__ W1,
    uint4* __restrict__ wpack)
{
    const int bid = blockIdx.x;
    const int tid = threadIdx.x;

    if (bid < PREP_REPACK) {
        // grid repack, 4 consecutive-x nodes per thread (float4 reads)
        const int base = (bid * 256 + tid) * 4;      // global node id, multiple of 4
        const int g    = base >> 18;                 // GR3 = 2^18
        const int node = base & (GR3 - 1);
        const int x    = node & 63;
        const float* p0 = grids + (size_t)g * 2 * GR3 + node;
        const float* p1 = p0 + GR3;
        const float4 c0 = *(const float4*)p0;
        const float4 c1 = *(const float4*)p1;
        float d0n, d1n;                              // neighbor of element x+3
        if (x == 60) { d0n = c0.w; d1n = c1.w; }     // x+3==63: clamp to self
        else         { d0n = p0[4]; d1n = p1[4]; }
        const float e0[5] = {c0.x, c0.y, c0.z, c0.w, d0n};
        const float e1[5] = {c1.x, c1.y, c1.z, c1.w, d1n};
        unsigned pk[5];
        #pragma unroll
        for (int i = 0; i < 5; ++i)
            pk[i] = f32_to_bf16_rne(e0[i]) | (f32_to_bf16_rne(e1[i]) << 16);
        uint4* dst = (uint4*)(gout + (size_t)g * GR3 + node);
        dst[0] = make_uint4(pk[0], pk[1], pk[1], pk[2]);
        dst[1] = make_uint4(pk[2], pk[3], pk[3], pk[4]);
    } else if (bid < PREP_REPACK + PREP_HIST) {
        // histogram + (key, rank) per point
        const int n = (bid - PREP_REPACK) * 256 + tid;
        const unsigned key = cell_of(xs[n*3+0], xs[n*3+1], xs[n*3+2]);
        const unsigned rank = atomicAdd(&bins[key], 1u);
        keyrank[n] = key | (rank << 15);
    } else if (bid == PREP_REPACK + PREP_HIST) {
        // transform matrices
        const int g = tid;
        if (g < NG) {
            float qx = rot[g*4+0], qy = rot[g*4+1], qz = rot[g*4+2], qw = rot[g*4+3];
            const float inv = 1.0f / sqrtf(qx*qx + qy*qy + qz*qz + qw*qw);
            qx *= inv; qy *= inv; qz *= inv; qw *= inv;
            const float sx = expf(scl[g*3+0]);
            const float sy = expf(scl[g*3+1]);
            const float sz = expf(scl[g*3+2]);
            float* m = mats + g * 12;
            m[0] = sx * (1.0f - 2.0f*(qy*qy + qz*qz));
            m[1] = sx * (2.0f*(qx*qy - qz*qw));
            m[2] = sx * (2.0f*(qx*qz + qy*qw));
            m[3] = sy * (2.0f*(qx*qy + qz*qw));
            m[4] = sy * (1.0f - 2.0f*(qx*qx + qz*qz));
            m[5] = sy * (2.0f*(qy*qz - qx*qw));
            m[6] = sz * (2.0f*(qx*qz - qy*qw));
            m[7] = sz * (2.0f*(qy*qz + qx*qw));
            m[8] = sz * (1.0f - 2.0f*(qx*qx + qy*qy));
            m[9]  = trn[g*3+0];
            m[10] = trn[g*3+1];
            m[11] = trn[g*3+2];
        }
    } else {
        // pack W0/W1 into MFMA B-fragment order (fp16).
        // B-frag: lane (c=lane&15, q=lane>>4) holds B[k=q*8+j][n=c], j=0..7.
        const int t = tid >> 6;          // ntile
        const int lane = tid & 63;
        const int q = lane >> 4, c = lane & 15;
        const int n = t * 16 + c;
        {
            unsigned u[4];
            #pragma unroll
            for (int jj = 0; jj < 4; ++jj) {
                const int k0 = q * 8 + 2 * jj;
                u[jj] = pack_h2(W0[k0 * NNODES + n], W0[(k0 + 1) * NNODES + n]);
            }
            wpack[t * 64 + lane] = make_uint4(u[0], u[1], u[2], u[3]);
        }
        #pragma unroll
        for (int ks = 0; ks < 2; ++ks) {
            unsigned u[4];
            #pragma unroll
            for (int jj = 0; jj < 4; ++jj) {
                const int k0 = ks * 32 + q * 8 + 2 * jj;
                u[jj] = pack_h2(W1[k0 * NNODES + n], W1[(k0 + 1) * NNODES + n]);
            }
            wpack[256 + (ks * 4 + t) * 64 + lane] = make_uint4(u[0], u[1], u[2], u[3]);
        }
    }
}

// ---- scan: exclusive prefix over 32768 bins, single block ----
__global__ __launch_bounds__(1024) void scan_kernel(unsigned* __restrict__ bins) {
    __shared__ unsigned s[1024];
    const int t = threadIdx.x;
    unsigned loc[32];
    unsigned sum = 0;
    #pragma unroll
    for (int i = 0; i < 32; ++i) { loc[i] = bins[t * 32 + i]; sum += loc[i]; }
    s[t] = sum;
    __syncthreads();
    for (int off = 1; off < 1024; off <<= 1) {
        unsigned v = (t >= off) ? s[t - off] : 0u;
        __syncthreads();
        s[t] += v;
        __syncthreads();
    }
    unsigned run = s[t] - sum;
    #pragma unroll
    for (int i = 0; i < 32; ++i) { bins[t * 32 + i] = run; run += loc[i]; }
}

// ---- scatter points into morton order using scanned bases ----
__global__ __launch_bounds__(256) void scatter_kernel(const float* __restrict__ xs,
                                                      const unsigned* __restrict__ bins,
                                                      const unsigned* __restrict__ keyrank,
                                                      float4* __restrict__ sorted) {
    const int n = blockIdx.x * 256 + threadIdx.x;
    if (n >= NPTS) return;
    const unsigned kr = keyrank[n];
    const unsigned key = kr & 0x7fffu;
    const unsigned rank = kr >> 15;
    const unsigned pos = bins[key] + rank;
    sorted[pos] = make_float4(xs[n*3+0], xs[n*3+1], xs[n*3+2], __int_as_float(n));
}

// ---- per-grid gather geometry ----
struct Geom {
    int i00, i01, i10, i11;
    float ax0, ax1, ay0, ay1, az0, az1;
    unsigned selhi, sello;
};

__device__ __forceinline__ Geom make_geom(const float* __restrict__ m,
                                          float px, float py, float pz, int g) {
    Geom G;
    const float tx = fmaf(m[0], px, fmaf(m[1], py, fmaf(m[2], pz, m[9])));
    const float ty = fmaf(m[3], px, fmaf(m[4], py, fmaf(m[5], pz, m[10])));
    const float tz = fmaf(m[6], px, fmaf(m[7], py, fmaf(m[8], pz, m[11])));
    const float fx = (tx + 1.0f) * 31.5f;
    const float fy = (ty + 1.0f) * 31.5f;
    const float fz = (tz + 1.0f) * 31.5f;
    const float x0f = floorf(fx), y0f = floorf(fy), z0f = floorf(fz);
    const float wx = fx - x0f, wy = fy - y0f, wz = fz - z0f;
    const int x0 = (int)x0f, y0 = (int)y0f, z0 = (int)z0f;
    G.ax0 = ((unsigned)x0       < 64u) ? (1.0f - wx) : 0.0f;
    G.ax1 = ((unsigned)(x0 + 1) < 64u) ? wx          : 0.0f;
    G.ay0 = ((unsigned)y0       < 64u) ? (1.0f - wy) : 0.0f;
    G.ay1 = ((unsigned)(y0 + 1) < 64u) ? wy          : 0.0f;
    G.az0 = ((unsigned)z0       < 64u) ? (1.0f - wz) : 0.0f;
    G.az1 = ((unsigned)(z0 + 1) < 64u) ? wz          : 0.0f;
    G.selhi = (x0 >= 63) ? 1u : 0u;
    G.sello = (x0 <= -1) ? 1u : 0u;
    const int xb  = min(max(x0, 0), 62);
    const int yc0 = min(max(y0, 0), 63),     yc1 = min(max(y0 + 1, 0), 63);
    const int zc0 = min(max(z0, 0), 63),     zc1 = min(max(z0 + 1, 0), 63);
    const int b = (g << 18) + xb;
    G.i00 = b + (zc0 << 12) + (yc0 << 6);
    G.i01 = b + (zc0 << 12) + (yc1 << 6);
    G.i10 = b + (zc1 << 12) + (yc0 << 6);
    G.i11 = b + (zc1 << 12) + (yc1 << 6);
    return G;
}

__device__ __forceinline__ void acc_pair(float& f0, float& f1, const Geom& G,
                                         uint2 q, float wyz) {
    const unsigned v0 = G.selhi ? q.y : q.x;
    const unsigned v1 = G.sello ? q.x : q.y;
    float s0 = G.ax0 * __uint_as_float(v0 << 16);
    s0 = fmaf(G.ax1, __uint_as_float(v1 << 16), s0);
    f0 = fmaf(wyz, s0, f0);
    float s1 = G.ax0 * __uint_as_float(v0 & 0xffff0000u);
    s1 = fmaf(G.ax1, __uint_as_float(v1 & 0xffff0000u), s1);
    f1 = fmaf(wyz, s1, f1);
}

// ---- main fused kernel: gather (VALU) + MLP layers 0/1 on MFMA ----
// LDS stages are type-punned (uint4/half8/unsigned/ushort views of one arena):
// hipcc has strict-aliasing TBAA, so every stage boundary gets a
// __syncthreads() memory fence to forbid cross-stage reordering. Control
// flow is block-uniform throughout, so the barriers are safe.
// launch_bounds(256,4): LDS 34816 B/block allows 4 blocks/CU = 16 waves/CU.
constexpr int ARENA_H = 64 * 66;       // ushorts per wave arena (h0 [node][pt], stride 66)
constexpr int FSTRIDE = 40;            // feats row stride in halves (bank-conflict pad)

__global__ __launch_bounds__(256, 4) void amgsrn_main(
    const float4* __restrict__ sorted,
    const uint2*  __restrict__ gridsP,
    const float*  __restrict__ mats,
    const uint4*  __restrict__ wpack,
    const float*  __restrict__ b0,
    const float*  __restrict__ b1,
    const float*  __restrict__ W2,
    const float*  __restrict__ b2,
    float* __restrict__ out)
{
    __shared__ unsigned short sh[4 * ARENA_H];
    __shared__ float yS[256];

    const int tid  = threadIdx.x;
    const int lane = tid & 63;
    const int wv   = tid >> 6;
    const int c    = lane & 15;
    const int q    = lane >> 4;
    unsigned short* wa = sh + wv * ARENA_H;

    const int n = blockIdx.x * 256 + tid;          // NPTS % 256 == 0: always valid
    const float4 p = sorted[n];
    const float px = p.x, py = p.y, pz = p.z;
    const int orig = __float_as_int(p.w);

    // ---- gather: 16 grids -> fp16-packed feature pairs (registers, const-indexed)
    unsigned pk[NG];
    Geom G = make_geom(mats, px, py, pz, 0);
    uint2 q00 = gridsP[G.i00], q01 = gridsP[G.i01];
    uint2 q10 = gridsP[G.i10], q11 = gridsP[G.i11];
    #pragma unroll
    for (int g = 0; g < NG; ++g) {
        Geom Gn;
        uint2 n00, n01, n10, n11;
        if (g + 1 < NG) {
            Gn = make_geom(mats + (g + 1) * 12, px, py, pz, g + 1);
            n00 = gridsP[Gn.i00]; n01 = gridsP[Gn.i01];
            n10 = gridsP[Gn.i10]; n11 = gridsP[Gn.i11];
        }
        float f0 = 0.0f, f1 = 0.0f;
        acc_pair(f0, f1, G, q00, G.az0 * G.ay0);
        acc_pair(f0, f1, G, q01, G.az0 * G.ay1);
        acc_pair(f0, f1, G, q10, G.az1 * G.ay0);
        acc_pair(f0, f1, G, q11, G.az1 * G.ay1);
        pk[g] = pack_h2(f0, f1);                   // feat 2g (low), 2g+1 (high)
        if (g + 1 < NG) {
            G = Gn;
            q00 = n00; q01 = n01; q10 = n10; q11 = n11;
        }
    }

    // ---- stage feats to LDS [pt][32 halves], row stride FSTRIDE halves
    {
        uint4* dst = (uint4*)(wa + lane * FSTRIDE); // 80B-aligned -> 16B-aligned
        dst[0] = make_uint4(pk[0],  pk[1],  pk[2],  pk[3]);
        dst[1] = make_uint4(pk[4],  pk[5],  pk[6],  pk[7]);
        dst[2] = make_uint4(pk[8],  pk[9],  pk[10], pk[11]);
        dst[3] = make_uint4(pk[12], pk[13], pk[14], pk[15]);
    }
    __syncthreads();   // fence: feats writes (uint4) -> A0 reads (half8)

    // ---- A0 fragments: A[m=pt][k=feat], lane holds pt=m*16+c, k=q*8..q*8+7
    half8 a0[4];
    #pragma unroll
    for (int m = 0; m < 4; ++m)
        a0[m] = *(const half8*)(wa + (m * 16 + c) * FSTRIDE + q * 8);

    // ---- B fragments + bias/W2 lane constants
    half8 b0f[4], b1f[2][4];
    #pragma unroll
    for (int t = 0; t < 4; ++t)
        b0f[t] = __builtin_bit_cast(half8, wpack[t * 64 + lane]);
    #pragma unroll
    for (int ks = 0; ks < 2; ++ks)
        #pragma unroll
        for (int t = 0; t < 4; ++t)
            b1f[ks][t] = __builtin_bit_cast(half8, wpack[256 + (ks * 4 + t) * 64 + lane]);
    float b0v[4], b1v[4], w2v[4];
    #pragma unroll
    for (int t = 0; t < 4; ++t) {
        b0v[t] = b0[t * 16 + c];
        b1v[t] = b1[t * 16 + c];
        w2v[t] = W2[t * 16 + c];
    }
    const float b2s = b2[0];

    __syncthreads();   // fence: A0 reads complete before layer-0 stores reuse the arena

    // ---- layer 0: 16 MFMA; D[pt][node]: col=node(c), rows=pt (q*4+reg)
    // store relu(h0) as fp16 to LDS [node][pt] (stride 66 halves)
    #pragma unroll
    for (int t = 0; t < 4; ++t) {
        #pragma unroll
        for (int m = 0; m < 4; ++m) {
            floatx4 acc = {b0v[t], b0v[t], b0v[t], b0v[t]};
            acc = __builtin_amdgcn_mfma_f32_16x16x32_f16(a0[m], b0f[t], acc, 0, 0, 0);
            const int node = t * 16 + c;
            const int pt   = m * 16 + q * 4;
            unsigned* w32 = (unsigned*)(wa + node * 66 + pt);  // 4B-aligned
            w32[0] = pack_h2(fmaxf(acc[0], 0.0f), fmaxf(acc[1], 0.0f));
            w32[1] = pack_h2(fmaxf(acc[2], 0.0f), fmaxf(acc[3], 0.0f));
        }
    }
    __syncthreads();   // fence: h0 writes (unsigned) -> A1 reads (ushort)

    // ---- A1 fragments: A[m=pt][k=node], k = ks*32 + q*8 + j
    half8 a1[4][2];
    #pragma unroll
    for (int m = 0; m < 4; ++m) {
        #pragma unroll
        for (int ks = 0; ks < 2; ++ks) {
            unsigned u[4];
            #pragma unroll
            for (int jj = 0; jj < 4; ++jj) {
                const int k0 = ks * 32 + q * 8 + 2 * jj;
                const unsigned lo = wa[k0 * 66 + m * 16 + c];
                const unsigned hi = wa[(k0 + 1) * 66 + m * 16 + c];
                u[jj] = lo | (hi << 16);
            }
            a1[m][ks] = __builtin_bit_cast(half8, make_uint4(u[0], u[1], u[2], u[3]));
        }
    }

    // ---- layer 1 (32 MFMA) + layer 2 folded into epilogue on D-registers
    float p4[4][4];
    #pragma unroll
    for (int m = 0; m < 4; ++m)
        #pragma unroll
        for (int r = 0; r < 4; ++r) p4[m][r] = 0.0f;

    #pragma unroll
    for (int t = 0; t < 4; ++t) {
        #pragma unroll
        for (int m = 0; m < 4; ++m) {
            floatx4 acc = {b1v[t], b1v[t], b1v[t], b1v[t]};
            acc = __builtin_amdgcn_mfma_f32_16x16x32_f16(a1[m][0], b1f[0][t], acc, 0, 0, 0);
            acc = __builtin_amdgcn_mfma_f32_16x16x32_f16(a1[m][1], b1f[1][t], acc, 0, 0, 0);
            #pragma unroll
            for (int r = 0; r < 4; ++r)
                p4[m][r] = fmaf(fmaxf(acc[r], 0.0f), w2v[t], p4[m][r]);
        }
    }

    // reduce partials across the 16 cols (lanes differing in low 4 bits)
    #pragma unroll
    for (int m = 0; m < 4; ++m)
        #pragma unroll
        for (int r = 0; r < 4; ++r) {
            float v = p4[m][r];
            v += __shfl_xor(v, 1, 64);
            v += __shfl_xor(v, 2, 64);
            v += __shfl_xor(v, 4, 64);
            v += __shfl_xor(v, 8, 64);
            p4[m][r] = v + b2s;
        }

    // lane c==0 of each quad publishes its 16 point results
    if (c == 0) {
        #pragma unroll
        for (int m = 0; m < 4; ++m)
            #pragma unroll
            for (int r = 0; r < 4; ++r)
                yS[wv * 64 + m * 16 + q * 4 + r] = p4[m][r];
    }
    __syncthreads();   // fence: yS writes -> yS reads
    out[orig] = yS[tid];
}

// ---- fallback (unsorted, original layout, pure fp32) used if ws too small ----
__global__ __launch_bounds__(256, 3) void amgsrn_fused_fallback(
    const float* __restrict__ xs,
    const float* __restrict__ rot,
    const float* __restrict__ scl,
    const float* __restrict__ trn,
    const float* __restrict__ grids,
    const float* __restrict__ W0,
    const float* __restrict__ b0,
    const float* __restrict__ W1,
    const float* __restrict__ b1,
    const float* __restrict__ W2,
    const float* __restrict__ b2,
    float* __restrict__ out)
{
    __shared__ float sM[NG][12];
    const int tid = threadIdx.x;
    if (tid < NG) {
        const int g = tid;
        float qx = rot[g*4+0], qy = rot[g*4+1], qz = rot[g*4+2], qw = rot[g*4+3];
        const float inv = 1.0f / sqrtf(qx*qx + qy*qy + qz*qz + qw*qw);
        qx *= inv; qy *= inv; qz *= inv; qw *= inv;
        const float sx = expf(scl[g*3+0]);
        const float sy = expf(scl[g*3+1]);
        const float sz = expf(scl[g*3+2]);
        sM[g][0] = sx * (1.0f - 2.0f*(qy*qy + qz*qz));
        sM[g][1] = sx * (2.0f*(qx*qy - qz*qw));
        sM[g][2] = sx * (2.0f*(qx*qz + qy*qw));
        sM[g][3] = sy * (2.0f*(qx*qy + qz*qw));
        sM[g][4] = sy * (1.0f - 2.0f*(qx*qx + qz*qz));
        sM[g][5] = sy * (2.0f*(qy*qz - qx*qw));
        sM[g][6] = sz * (2.0f*(qx*qz - qy*qw));
        sM[g][7] = sz * (2.0f*(qy*qz + qx*qw));
        sM[g][8] = sz * (1.0f - 2.0f*(qx*qx + qy*qy));
        sM[g][9]  = trn[g*3+0];
        sM[g][10] = trn[g*3+1];
        sM[g][11] = trn[g*3+2];
    }
    __syncthreads();

    const int n = blockIdx.x * blockDim.x + tid;
    if (n >= NPTS) return;
    const float px = xs[n*3+0];
    const float py = xs[n*3+1];
    const float pz = xs[n*3+2];

    float h0[NNODES];
    #pragma unroll
    for (int j = 0; j < NNODES; ++j) h0[j] = b0[j];

    #pragma unroll
    for (int g = 0; g < NG; ++g) {
        const float* m = sM[g];
        const float tx = m[0]*px + m[1]*py + m[2]*pz + m[9];
        const float ty = m[3]*px + m[4]*py + m[5]*pz + m[10];
        const float tz = m[6]*px + m[7]*py + m[8]*pz + m[11];
        const float fx = (tx + 1.0f) * 31.5f;
        const float fy = (ty + 1.0f) * 31.5f;
        const float fz = (tz + 1.0f) * 31.5f;
        const float x0f = floorf(fx), y0f = floorf(fy), z0f = floorf(fz);
        const float wx = fx - x0f, wy = fy - y0f, wz = fz - z0f;
        const int x0 = (int)x0f, y0 = (int)y0f, z0 = (int)z0f;
        const float* gb = grids + (size_t)g * (size_t)(2 * GR3);
        float f0 = 0.0f, f1 = 0.0f;
        #pragma unroll
        for (int dz = 0; dz < 2; ++dz) {
            #pragma unroll
            for (int dy = 0; dy < 2; ++dy) {
                #pragma unroll
                for (int dx = 0; dx < 2; ++dx) {
                    const int xi = x0 + dx, yi = y0 + dy, zi = z0 + dz;
                    const bool valid = ((unsigned)xi < (unsigned)GR) &
                                       ((unsigned)yi < (unsigned)GR) &
                                       ((unsigned)zi < (unsigned)GR);
                    const int xc = min(max(xi, 0), GR-1);
                    const int yc = min(max(yi, 0), GR-1);
                    const int zc = min(max(zi, 0), GR-1);
                    float w = (dx ? wx : 1.0f - wx) *
                              (dy ? wy : 1.0f - wy) *
                              (dz ? wz : 1.0f - wz);
                    w = valid ? w : 0.0f;
                    const int idx = (zc * GR + yc) * GR + xc;
                    f0 = fmaf(w, gb[idx], f0);
                    f1 = fmaf(w, gb[idx + GR3], f1);
                }
            }
        }
        const float* w0a = W0 + (2*g    ) * NNODES;
        const float* w0b = W0 + (2*g + 1) * NNODES;
        #pragma unroll
        for (int j = 0; j < NNODES; ++j)
            h0[j] = fmaf(f1, w0b[j], fmaf(f0, w0a[j], h0[j]));
    }
    #pragma unroll
    for (int j = 0; j < NNODES; ++j) h0[j] = fmaxf(h0[j], 0.0f);

    float y = b2[0];
    #pragma unroll
    for (int half = 0; half < 2; ++half) {
        float h1[32];
        #pragma unroll
        for (int j = 0; j < 32; ++j) h1[j] = b1[half * 32 + j];
        #pragma unroll
        for (int k = 0; k < NNODES; ++k) {
            const float a = h0[k];
            const float* w = W1 + k * NNODES + half * 32;
            #pragma unroll
            for (int j = 0; j < 32; ++j) h1[j] = fmaf(a, w[j], h1[j]);
        }
        #pragma unroll
        for (int j = 0; j < 32; ++j) y = fmaf(fmaxf(h1[j], 0.0f), W2[half * 32 + j], y);
    }

    out[n] = y;
}

extern "C" void kernel_launch(void* const* d_in, const int* in_sizes, int n_in,
                              void* d_out, int out_size, void* d_ws, size_t ws_size,
                              hipStream_t stream) {
    const float* xs  = (const float*)d_in[0];
    const float* rot = (const float*)d_in[1];
    const float* scl = (const float*)d_in[2];
    const float* trn = (const float*)d_in[3];
    const float* gr  = (const float*)d_in[4];
    const float* W0  = (const float*)d_in[5];
    const float* b0  = (const float*)d_in[6];
    const float* W1  = (const float*)d_in[7];
    const float* b1  = (const float*)d_in[8];
    const float* W2  = (const float*)d_in[9];
    const float* b2  = (const float*)d_in[10];
    float* out = (float*)d_out;

    if (ws_size < WS_TOTAL) {
        dim3 grid((NPTS + 255) / 256), block(256);
        hipLaunchKernelGGL(amgsrn_fused_fallback, grid, block, 0, stream,
                           xs, rot, scl, trn, gr, W0, b0, W1, b1, W2, b2, out);
        return;
    }

    char* ws = (char*)d_ws;
    uint2*    gridsP  = (uint2*)(ws);
    float4*   sorted  = (float4*)(ws + WS_SORT);
    unsigned* keyrank = (unsigned*)(ws + WS_KEYR);
    unsigned* bins    = (unsigned*)(ws + WS_BINS);
    float*    mats    = (float*)(ws + WS_MATS);
    uint4*    wpack   = (uint4*)(ws + WS_WPACK);

    hipMemsetAsync(bins, 0, BINS_BYTES, stream);
    hipLaunchKernelGGL(prep_kernel, dim3(PREP_REPACK + PREP_HIST + 2), dim3(256), 0, stream,
                       gr, gridsP, xs, bins, keyrank,
                       rot, scl, trn, mats, W0, W1, wpack);
    hipLaunchKernelGGL(scan_kernel, dim3(1), dim3(1024), 0, stream, bins);
    hipLaunchKernelGGL(scatter_kernel, dim3(NPTS / 256), dim3(256), 0, stream,
                       xs, bins, keyrank, sorted);
    hipLaunchKernelGGL(amgsrn_main, dim3(NPTS / 256), dim3(256), 0, stream,
                       sorted, gridsP, mats, wpack, b0, b1, W2, b2, out);
}

// Round 9
// 189.155 us; speedup vs baseline: 4.1872x; 1.0405x over previous
//
#include <hip/hip_runtime.h>
#include <cstddef>
#include <cstdint>

constexpr int NPTS   = 524288;
constexpr int NG     = 16;
constexpr int GR     = 64;
constexpr int GR3    = GR * GR * GR;   // 262144
constexpr int NNODES = 64;
constexpr int NBINS  = 32768;          // 32^3 spatial cells, morton order

// workspace layout (bytes)
constexpr size_t GRIDS_BYTES = (size_t)NG * GR3 * 8;        // 32 MB: x-pair replicated bf16x2 (uint2/node)
constexpr size_t WS_SORT     = GRIDS_BYTES;
constexpr size_t SORT_BYTES  = (size_t)NPTS * 16;           // 8 MB float4
constexpr size_t WS_KEYR     = WS_SORT + SORT_BYTES;
constexpr size_t KEYR_BYTES  = (size_t)NPTS * 4;            // 2 MB key|rank
constexpr size_t WS_BINS     = WS_KEYR + KEYR_BYTES;
constexpr size_t BINS_BYTES  = (size_t)NBINS * 4;
constexpr size_t WS_MATS     = WS_BINS + BINS_BYTES;
constexpr size_t MATS_BYTES  = 1024;                        // 16*12 floats, padded
constexpr size_t WS_WPACK    = WS_MATS + MATS_BYTES;
constexpr size_t WPACK_BYTES = (size_t)(256 + 512) * 16;    // B0: 256 uint4, B1: 512 uint4
constexpr size_t WS_PART     = WS_WPACK + WPACK_BYTES;
constexpr size_t PART_BYTES  = 128 * 4;                     // scan block partials
constexpr size_t WS_TOTAL    = WS_PART + PART_BYTES;

// prep kernel block-role ranges
constexpr int PREP_REPACK = 4096;      // 4096 blocks * 256 thr * 4 nodes = NG*GR3
constexpr int PREP_HIST   = 2048;      // 2048 blocks * 256 thr = NPTS

typedef _Float16 half8 __attribute__((ext_vector_type(8)));
typedef float    floatx4 __attribute__((ext_vector_type(4)));

__device__ __forceinline__ unsigned part1by2(unsigned x) {
    x &= 0x3ff;
    x = (x | (x << 16)) & 0x030000FF;
    x = (x | (x <<  8)) & 0x0300F00F;
    x = (x | (x <<  4)) & 0x030C30C3;
    x = (x | (x <<  2)) & 0x09249249;
    return x;
}

__device__ __forceinline__ unsigned cell_of(float px, float py, float pz) {
    int cx = (int)((px + 1.0f) * 16.0f); cx = min(max(cx, 0), 31);
    int cy = (int)((py + 1.0f) * 16.0f); cy = min(max(cy, 0), 31);
    int cz = (int)((pz + 1.0f) * 16.0f); cz = min(max(cz, 0), 31);
    return part1by2((unsigned)cx) | (part1by2((unsigned)cy) << 1) | (part1by2((unsigned)cz) << 2);
}

__device__ __forceinline__ unsigned f32_to_bf16_rne(float f) {
    unsigned u = __float_as_uint(f);
    return (u + 0x7fffu + ((u >> 16) & 1u)) >> 16;
}

// pack two floats to fp16x2 (RNE)
__device__ __forceinline__ unsigned pack_h2(float a, float b) {
    unsigned short ua = __builtin_bit_cast(unsigned short, (_Float16)a);
    unsigned short ub = __builtin_bit_cast(unsigned short, (_Float16)b);
    return (unsigned)ua | ((unsigned)ub << 16);
}

__device__ __forceinline__ unsigned short f32_to_h16(float a) {
    return __builtin_bit_cast(unsigned short, (_Float16)a);
}

// ---- fused prep: repack grids | hist | mats | pack weights (independent) ----
__global__ __launch_bounds__(256) void prep_kernel(
    const float* __restrict__ grids, uint2* __restrict__ gout,
    const float* __restrict__ xs, unsigned* __restrict__ bins,
    unsigned* __restrict__ keyrank,
    const float* __restrict__ rot, const float* __restrict__ scl,
    const float* __restrict__ trn, float* __restrict__ mats,
    const float* __restrict__ W0, const float* __restrict__ W1,
    uint4* __restrict__ wpack)
{
    const int bid = blockIdx.x;
    const int tid = threadIdx.x;

    if (bid < PREP_REPACK) {
        // grid repack, 4 consecutive-x nodes per thread (float4 reads)
        const int base = (bid * 256 + tid) * 4;      // global node id, multiple of 4
        const int g    = base >> 18;                 // GR3 = 2^18
        const int node = base & (GR3 - 1);
        const int x    = node & 63;
        const float* p0 = grids + (size_t)g * 2 * GR3 + node;
        const float* p1 = p0 + GR3;
        const float4 c0 = *(const float4*)p0;
        const float4 c1 = *(const float4*)p1;
        float d0n, d1n;                              // neighbor of element x+3
        if (x == 60) { d0n = c0.w; d1n = c1.w; }     // x+3==63: clamp to self
        else         { d0n = p0[4]; d1n = p1[4]; }
        const float e0[5] = {c0.x, c0.y, c0.z, c0.w, d0n};
        const float e1[5] = {c1.x, c1.y, c1.z, c1.w, d1n};
        unsigned pk[5];
        #pragma unroll
        for (int i = 0; i < 5; ++i)
            pk[i] = f32_to_bf16_rne(e0[i]) | (f32_to_bf16_rne(e1[i]) << 16);
        uint4* dst = (uint4*)(gout + (size_t)g * GR3 + node);
        dst[0] = make_uint4(pk[0], pk[1], pk[1], pk[2]);
        dst[1] = make_uint4(pk[2], pk[3], pk[3], pk[4]);
    } else if (bid < PREP_REPACK + PREP_HIST) {
        // histogram + (key, rank) per point
        const int n = (bid - PREP_REPACK) * 256 + tid;
        const unsigned key = cell_of(xs[n*3+0], xs[n*3+1], xs[n*3+2]);
        const unsigned rank = atomicAdd(&bins[key], 1u);
        keyrank[n] = key | (rank << 15);
    } else if (bid == PREP_REPACK + PREP_HIST) {
        // transform matrices
        const int g = tid;
        if (g < NG) {
            float qx = rot[g*4+0], qy = rot[g*4+1], qz = rot[g*4+2], qw = rot[g*4+3];
            const float inv = 1.0f / sqrtf(qx*qx + qy*qy + qz*qz + qw*qw);
            qx *= inv; qy *= inv; qz *= inv; qw *= inv;
            const float sx = expf(scl[g*3+0]);
            const float sy = expf(scl[g*3+1]);
            const float sz = expf(scl[g*3+2]);
            float* m = mats + g * 12;
            m[0] = sx * (1.0f - 2.0f*(qy*qy + qz*qz));
            m[1] = sx * (2.0f*(qx*qy - qz*qw));
            m[2] = sx * (2.0f*(qx*qz + qy*qw));
            m[3] = sy * (2.0f*(qx*qy + qz*qw));
            m[4] = sy * (1.0f - 2.0f*(qx*qx + qz*qz));
            m[5] = sy * (2.0f*(qy*qz - qx*qw));
            m[6] = sz * (2.0f*(qx*qz - qy*qw));
            m[7] = sz * (2.0f*(qy*qz + qx*qw));
            m[8] = sz * (1.0f - 2.0f*(qx*qx + qy*qy));
            m[9]  = trn[g*3+0];
            m[10] = trn[g*3+1];
            m[11] = trn[g*3+2];
        }
    } else {
        // pack W0/W1 into MFMA B-fragment order (fp16).
        // B-frag: lane (c=lane&15, q=lane>>4) holds B[k=q*8+j][n=c], j=0..7.
        const int t = tid >> 6;          // ntile
        const int lane = tid & 63;
        const int q = lane >> 4, c = lane & 15;
        const int n = t * 16 + c;
        {
            unsigned u[4];
            #pragma unroll
            for (int jj = 0; jj < 4; ++jj) {
                const int k0 = q * 8 + 2 * jj;
                u[jj] = pack_h2(W0[k0 * NNODES + n], W0[(k0 + 1) * NNODES + n]);
            }
            wpack[t * 64 + lane] = make_uint4(u[0], u[1], u[2], u[3]);
        }
        #pragma unroll
        for (int ks = 0; ks < 2; ++ks) {
            unsigned u[4];
            #pragma unroll
            for (int jj = 0; jj < 4; ++jj) {
                const int k0 = ks * 32 + q * 8 + 2 * jj;
                u[jj] = pack_h2(W1[k0 * NNODES + n], W1[(k0 + 1) * NNODES + n]);
            }
            wpack[256 + (ks * 4 + t) * 64 + lane] = make_uint4(u[0], u[1], u[2], u[3]);
        }
    }
}

// ---- scanA: per-block exclusive scan of 256 bins + block partial ----
__global__ __launch_bounds__(256) void scanA_kernel(unsigned* __restrict__ bins,
                                                    unsigned* __restrict__ part) {
    __shared__ unsigned s[256];
    const int t = threadIdx.x;
    const int base = blockIdx.x * 256;
    const unsigned v = bins[base + t];
    s[t] = v;
    __syncthreads();
    for (int off = 1; off < 256; off <<= 1) {
        unsigned u = (t >= off) ? s[t - off] : 0u;
        __syncthreads();
        s[t] += u;
        __syncthreads();
    }
    bins[base + t] = s[t] - v;             // within-block exclusive
    if (t == 255) part[blockIdx.x] = s[255];
}

// ---- scanB: exclusive scan of the 128 block partials ----
__global__ __launch_bounds__(128) void scanB_kernel(unsigned* __restrict__ part) {
    __shared__ unsigned s[128];
    const int t = threadIdx.x;
    const unsigned v = part[t];
    s[t] = v;
    __syncthreads();
    for (int off = 1; off < 128; off <<= 1) {
        unsigned u = (t >= off) ? s[t - off] : 0u;
        __syncthreads();
        s[t] += u;
        __syncthreads();
    }
    part[t] = s[t] - v;
}

// ---- scatter points into morton order using two-level scanned bases ----
__global__ __launch_bounds__(256) void scatter_kernel(const float* __restrict__ xs,
                                                      const unsigned* __restrict__ bins,
                                                      const unsigned* __restrict__ part,
                                                      const unsigned* __restrict__ keyrank,
                                                      float4* __restrict__ sorted) {
    const int n = blockIdx.x * 256 + threadIdx.x;
    if (n >= NPTS) return;
    const unsigned kr = keyrank[n];
    const unsigned key = kr & 0x7fffu;
    const unsigned rank = kr >> 15;
    const unsigned pos = part[key >> 8] + bins[key] + rank;
    sorted[pos] = make_float4(xs[n*3+0], xs[n*3+1], xs[n*3+2], __int_as_float(n));
}

// ---- per-grid gather geometry ----
struct Geom {
    int i00, i01, i10, i11;
    float ax0, ax1, ay0, ay1, az0, az1;
    unsigned selhi, sello;
};

__device__ __forceinline__ Geom make_geom(const float* __restrict__ m,
                                          float px, float py, float pz, int g) {
    Geom G;
    const float tx = fmaf(m[0], px, fmaf(m[1], py, fmaf(m[2], pz, m[9])));
    const float ty = fmaf(m[3], px, fmaf(m[4], py, fmaf(m[5], pz, m[10])));
    const float tz = fmaf(m[6], px, fmaf(m[7], py, fmaf(m[8], pz, m[11])));
    const float fx = (tx + 1.0f) * 31.5f;
    const float fy = (ty + 1.0f) * 31.5f;
    const float fz = (tz + 1.0f) * 31.5f;
    const float x0f = floorf(fx), y0f = floorf(fy), z0f = floorf(fz);
    const float wx = fx - x0f, wy = fy - y0f, wz = fz - z0f;
    const int x0 = (int)x0f, y0 = (int)y0f, z0 = (int)z0f;
    G.ax0 = ((unsigned)x0       < 64u) ? (1.0f - wx) : 0.0f;
    G.ax1 = ((unsigned)(x0 + 1) < 64u) ? wx          : 0.0f;
    G.ay0 = ((unsigned)y0       < 64u) ? (1.0f - wy) : 0.0f;
    G.ay1 = ((unsigned)(y0 + 1) < 64u) ? wy          : 0.0f;
    G.az0 = ((unsigned)z0       < 64u) ? (1.0f - wz) : 0.0f;
    G.az1 = ((unsigned)(z0 + 1) < 64u) ? wz          : 0.0f;
    G.selhi = (x0 >= 63) ? 1u : 0u;
    G.sello = (x0 <= -1) ? 1u : 0u;
    const int xb  = min(max(x0, 0), 62);
    const int yc0 = min(max(y0, 0), 63),     yc1 = min(max(y0 + 1, 0), 63);
    const int zc0 = min(max(z0, 0), 63),     zc1 = min(max(z0 + 1, 0), 63);
    const int b = (g << 18) + xb;
    G.i00 = b + (zc0 << 12) + (yc0 << 6);
    G.i01 = b + (zc0 << 12) + (yc1 << 6);
    G.i10 = b + (zc1 << 12) + (yc0 << 6);
    G.i11 = b + (zc1 << 12) + (yc1 << 6);
    return G;
}

__device__ __forceinline__ void acc_pair(float& f0, float& f1, const Geom& G,
                                         uint2 q, float wyz) {
    const unsigned v0 = G.selhi ? q.y : q.x;
    const unsigned v1 = G.sello ? q.x : q.y;
    float s0 = G.ax0 * __uint_as_float(v0 << 16);
    s0 = fmaf(G.ax1, __uint_as_float(v1 << 16), s0);
    f0 = fmaf(wyz, s0, f0);
    float s1 = G.ax0 * __uint_as_float(v0 & 0xffff0000u);
    s1 = fmaf(G.ax1, __uint_as_float(v1 & 0xffff0000u), s1);
    f1 = fmaf(wyz, s1, f1);
}

// ---- main fused kernel: gather (VALU, depth-2 prefetch) + MLP on MFMA ----
// LDS arena per wave (wave-private), type-punned across stages ->
// __syncthreads() fence at every stage boundary (block-uniform control flow).
// h0 is stored [pt][node] (stride HSTR halves) so both A0 and A1 fragments
// are contiguous ds_read_b128.
constexpr int HSTR    = 72;            // h0 row stride in halves (16B-aligned rows, pad 8)
constexpr int ARENA_H = 64 * HSTR;     // ushorts per wave arena
constexpr int FSTRIDE = 40;            // feats row stride in halves

__global__ __launch_bounds__(256, 4) void amgsrn_main(
    const float4* __restrict__ sorted,
    const uint2*  __restrict__ gridsP,
    const float*  __restrict__ mats,
    const uint4*  __restrict__ wpack,
    const float*  __restrict__ b0,
    const float*  __restrict__ b1,
    const float*  __restrict__ W2,
    const float*  __restrict__ b2,
    float* __restrict__ out)
{
    __shared__ unsigned short sh[4 * ARENA_H];
    __shared__ float yS[256];

    const int tid  = threadIdx.x;
    const int lane = tid & 63;
    const int wv   = tid >> 6;
    const int c    = lane & 15;
    const int q    = lane >> 4;
    unsigned short* wa = sh + wv * ARENA_H;

    const int n = blockIdx.x * 256 + tid;          // NPTS % 256 == 0: always valid
    const float4 p = sorted[n];
    const float px = p.x, py = p.y, pz = p.z;
    const int orig = __float_as_int(p.w);

    // ---- gather: 16 grids, depth-2 software pipeline
    unsigned pk[NG];
    Geom Ga = make_geom(mats, px, py, pz, 0);
    uint2 a00 = gridsP[Ga.i00], a01 = gridsP[Ga.i01];
    uint2 a10 = gridsP[Ga.i10], a11 = gridsP[Ga.i11];
    Geom Gb = make_geom(mats + 12, px, py, pz, 1);
    uint2 b00 = gridsP[Gb.i00], b01 = gridsP[Gb.i01];
    uint2 b10 = gridsP[Gb.i10], b11 = gridsP[Gb.i11];
    #pragma unroll
    for (int g = 0; g < NG; ++g) {
        Geom Gn;
        uint2 n00, n01, n10, n11;
        if (g + 2 < NG) {
            Gn = make_geom(mats + (g + 2) * 12, px, py, pz, g + 2);
            n00 = gridsP[Gn.i00]; n01 = gridsP[Gn.i01];
            n10 = gridsP[Gn.i10]; n11 = gridsP[Gn.i11];
        }
        float f0 = 0.0f, f1 = 0.0f;
        acc_pair(f0, f1, Ga, a00, Ga.az0 * Ga.ay0);
        acc_pair(f0, f1, Ga, a01, Ga.az0 * Ga.ay1);
        acc_pair(f0, f1, Ga, a10, Ga.az1 * Ga.ay0);
        acc_pair(f0, f1, Ga, a11, Ga.az1 * Ga.ay1);
        pk[g] = pack_h2(f0, f1);                   // feat 2g (low), 2g+1 (high)
        Ga = Gb; a00 = b00; a01 = b01; a10 = b10; a11 = b11;
        if (g + 2 < NG) {
            Gb = Gn; b00 = n00; b01 = n01; b10 = n10; b11 = n11;
        }
    }

    // ---- stage feats to LDS [pt][32 halves], row stride FSTRIDE halves
    {
        uint4* dst = (uint4*)(wa + lane * FSTRIDE); // 80B-aligned -> 16B-aligned
        dst[0] = make_uint4(pk[0],  pk[1],  pk[2],  pk[3]);
        dst[1] = make_uint4(pk[4],  pk[5],  pk[6],  pk[7]);
        dst[2] = make_uint4(pk[8],  pk[9],  pk[10], pk[11]);
        dst[3] = make_uint4(pk[12], pk[13], pk[14], pk[15]);
    }
    __syncthreads();   // fence: feats writes (uint4) -> A0 reads (half8)

    // ---- A0 fragments: A[m=pt][k=feat], lane holds pt=m*16+c, k=q*8..q*8+7
    half8 a0[4];
    #pragma unroll
    for (int m = 0; m < 4; ++m)
        a0[m] = *(const half8*)(wa + (m * 16 + c) * FSTRIDE + q * 8);

    // ---- B fragments + bias/W2 lane constants
    half8 b0f[4], b1f[2][4];
    #pragma unroll
    for (int t = 0; t < 4; ++t)
        b0f[t] = __builtin_bit_cast(half8, wpack[t * 64 + lane]);
    #pragma unroll
    for (int ks = 0; ks < 2; ++ks)
        #pragma unroll
        for (int t = 0; t < 4; ++t)
            b1f[ks][t] = __builtin_bit_cast(half8, wpack[256 + (ks * 4 + t) * 64 + lane]);
    float b0v[4], b1v[4], w2v[4];
    #pragma unroll
    for (int t = 0; t < 4; ++t) {
        b0v[t] = b0[t * 16 + c];
        b1v[t] = b1[t * 16 + c];
        w2v[t] = W2[t * 16 + c];
    }
    const float b2s = b2[0];

    __syncthreads();   // fence: A0 reads complete before layer-0 stores reuse the arena

    // ---- layer 0: 16 MFMA; D gives lane col=node(c+t*16), rows=pt(m*16+q*4+r)
    // store relu(h0) as fp16 to LDS [pt][node], stride HSTR halves
    #pragma unroll
    for (int t = 0; t < 4; ++t) {
        #pragma unroll
        for (int m = 0; m < 4; ++m) {
            floatx4 acc = {b0v[t], b0v[t], b0v[t], b0v[t]};
            acc = __builtin_amdgcn_mfma_f32_16x16x32_f16(a0[m], b0f[t], acc, 0, 0, 0);
            const int node = t * 16 + c;
            const int ptb  = m * 16 + q * 4;
            #pragma unroll
            for (int r = 0; r < 4; ++r)
                wa[(ptb + r) * HSTR + node] = f32_to_h16(fmaxf(acc[r], 0.0f));
        }
    }
    __syncthreads();   // fence: h0 writes (ushort) -> A1 reads (half8)

    // ---- A1 fragments: A[m=pt][k=node], contiguous b128 reads
    half8 a1[4][2];
    #pragma unroll
    for (int m = 0; m < 4; ++m)
        #pragma unroll
        for (int ks = 0; ks < 2; ++ks)
            a1[m][ks] = *(const half8*)(wa + (m * 16 + c) * HSTR + ks * 32 + q * 8);

    // ---- layer 1 (32 MFMA) + layer 2 folded into epilogue on D-registers
    float p4[4][4];
    #pragma unroll
    for (int m = 0; m < 4; ++m)
        #pragma unroll
        for (int r = 0; r < 4; ++r) p4[m][r] = 0.0f;

    #pragma unroll
    for (int t = 0; t < 4; ++t) {
        #pragma unroll
        for (int m = 0; m < 4; ++m) {
            floatx4 acc = {b1v[t], b1v[t], b1v[t], b1v[t]};
            acc = __builtin_amdgcn_mfma_f32_16x16x32_f16(a1[m][0], b1f[0][t], acc, 0, 0, 0);
            acc = __builtin_amdgcn_mfma_f32_16x16x32_f16(a1[m][1], b1f[1][t], acc, 0, 0, 0);
            #pragma unroll
            for (int r = 0; r < 4; ++r)
                p4[m][r] = fmaf(fmaxf(acc[r], 0.0f), w2v[t], p4[m][r]);
        }
    }

    // reduce partials across the 16 cols (lanes differing in low 4 bits)
    #pragma unroll
    for (int m = 0; m < 4; ++m)
        #pragma unroll
        for (int r = 0; r < 4; ++r) {
            float v = p4[m][r];
            v += __shfl_xor(v, 1, 64);
            v += __shfl_xor(v, 2, 64);
            v += __shfl_xor(v, 4, 64);
            v += __shfl_xor(v, 8, 64);
            p4[m][r] = v + b2s;
        }

    // lane c==0 of each quad publishes its 16 point results
    if (c == 0) {
        #pragma unroll
        for (int m = 0; m < 4; ++m)
            #pragma unroll
            for (int r = 0; r < 4; ++r)
                yS[wv * 64 + m * 16 + q * 4 + r] = p4[m][r];
    }
    __syncthreads();   // fence: yS writes -> yS reads
    out[orig] = yS[tid];
}

// ---- fallback (unsorted, original layout, pure fp32) used if ws too small ----
__global__ __launch_bounds__(256, 3) void amgsrn_fused_fallback(
    const float* __restrict__ xs,
    const float* __restrict__ rot,
    const float* __restrict__ scl,
    const float* __restrict__ trn,
    const float* __restrict__ grids,
    const float* __restrict__ W0,
    const float* __restrict__ b0,
    const float* __restrict__ W1,
    const float* __restrict__ b1,
    const float* __restrict__ W2,
    const float* __restrict__ b2,
    float* __restrict__ out)
{
    __shared__ float sM[NG][12];
    const int tid = threadIdx.x;
    if (tid < NG) {
        const int g = tid;
        float qx = rot[g*4+0], qy = rot[g*4+1], qz = rot[g*4+2], qw = rot[g*4+3];
        const float inv = 1.0f / sqrtf(qx*qx + qy*qy + qz*qz + qw*qw);
        qx *= inv; qy *= inv; qz *= inv; qw *= inv;
        const float sx = expf(scl[g*3+0]);
        const float sy = expf(scl[g*3+1]);
        const float sz = expf(scl[g*3+2]);
        sM[g][0] = sx * (1.0f - 2.0f*(qy*qy + qz*qz));
        sM[g][1] = sx * (2.0f*(qx*qy - qz*qw));
        sM[g][2] = sx * (2.0f*(qx*qz + qy*qw));
        sM[g][3] = sy * (2.0f*(qx*qy + qz*qw));
        sM[g][4] = sy * (1.0f - 2.0f*(qx*qx + qz*qz));
        sM[g][5] = sy * (2.0f*(qy*qz - qx*qw));
        sM[g][6] = sz * (2.0f*(qx*qz - qy*qw));
        sM[g][7] = sz * (2.0f*(qy*qz + qx*qw));
        sM[g][8] = sz * (1.0f - 2.0f*(qx*qx + qy*qy));
        sM[g][9]  = trn[g*3+0];
        sM[g][10] = trn[g*3+1];
        sM[g][11] = trn[g*3+2];
    }
    __syncthreads();

    const int n = blockIdx.x * blockDim.x + tid;
    if (n >= NPTS) return;
    const float px = xs[n*3+0];
    const float py = xs[n*3+1];
    const float pz = xs[n*3+2];

    float h0[NNODES];
    #pragma unroll
    for (int j = 0; j < NNODES; ++j) h0[j] = b0[j];

    #pragma unroll
    for (int g = 0; g < NG; ++g) {
        const float* m = sM[g];
        const float tx = m[0]*px + m[1]*py + m[2]*pz + m[9];
        const float ty = m[3]*px + m[4]*py + m[5]*pz + m[10];
        const float tz = m[6]*px + m[7]*py + m[8]*pz + m[11];
        const float fx = (tx + 1.0f) * 31.5f;
        const float fy = (ty + 1.0f) * 31.5f;
        const float fz = (tz + 1.0f) * 31.5f;
        const float x0f = floorf(fx), y0f = floorf(fy), z0f = floorf(fz);
        const float wx = fx - x0f, wy = fy - y0f, wz = fz - z0f;
        const int x0 = (int)x0f, y0 = (int)y0f, z0 = (int)z0f;
        const float* gb = grids + (size_t)g * (size_t)(2 * GR3);
        float f0 = 0.0f, f1 = 0.0f;
        #pragma unroll
        for (int dz = 0; dz < 2; ++dz) {
            #pragma unroll
            for (int dy = 0; dy < 2; ++dy) {
                #pragma unroll
                for (int dx = 0; dx < 2; ++dx) {
                    const int xi = x0 + dx, yi = y0 + dy, zi = z0 + dz;
                    const bool valid = ((unsigned)xi < (unsigned)GR) &
                                       ((unsigned)yi < (unsigned)GR) &
                                       ((unsigned)zi < (unsigned)GR);
                    const int xc = min(max(xi, 0), GR-1);
                    const int yc = min(max(yi, 0), GR-1);
                    const int zc = min(max(zi, 0), GR-1);
                    float w = (dx ? wx : 1.0f - wx) *
                              (dy ? wy : 1.0f - wy) *
                              (dz ? wz : 1.0f - wz);
                    w = valid ? w : 0.0f;
                    const int idx = (zc * GR + yc) * GR + xc;
                    f0 = fmaf(w, gb[idx], f0);
                    f1 = fmaf(w, gb[idx + GR3], f1);
                }
            }
        }
        const float* w0a = W0 + (2*g    ) * NNODES;
        const float* w0b = W0 + (2*g + 1) * NNODES;
        #pragma unroll
        for (int j = 0; j < NNODES; ++j)
            h0[j] = fmaf(f1, w0b[j], fmaf(f0, w0a[j], h0[j]));
    }
    #pragma unroll
    for (int j = 0; j < NNODES; ++j) h0[j] = fmaxf(h0[j], 0.0f);

    float y = b2[0];
    #pragma unroll
    for (int half = 0; half < 2; ++half) {
        float h1[32];
        #pragma unroll
        for (int j = 0; j < 32; ++j) h1[j] = b1[half * 32 + j];
        #pragma unroll
        for (int k = 0; k < NNODES; ++k) {
            const float a = h0[k];
            const float* w = W1 + k * NNODES + half * 32;
            #pragma unroll
            for (int j = 0; j < 32; ++j) h1[j] = fmaf(a, w[j], h1[j]);
        }
        #pragma unroll
        for (int j = 0; j < 32; ++j) y = fmaf(fmaxf(h1[j], 0.0f), W2[half * 32 + j], y);
    }

    out[n] = y;
}

extern "C" void kernel_launch(void* const* d_in, const int* in_sizes, int n_in,
                              void* d_out, int out_size, void* d_ws, size_t ws_size,
                              hipStream_t stream) {
    const float* xs  = (const float*)d_in[0];
    const float* rot = (const float*)d_in[1];
    const float* scl = (const float*)d_in[2];
    const float* trn = (const float*)d_in[3];
    const float* gr  = (const float*)d_in[4];
    const float* W0  = (const float*)d_in[5];
    const float* b0  = (const float*)d_in[6];
    const float* W1  = (const float*)d_in[7];
    const float* b1  = (const float*)d_in[8];
    const float* W2  = (const float*)d_in[9];
    const float* b2  = (const float*)d_in[10];
    float* out = (float*)d_out;

    if (ws_size < WS_TOTAL) {
        dim3 grid((NPTS + 255) / 256), block(256);
        hipLaunchKernelGGL(amgsrn_fused_fallback, grid, block, 0, stream,
                           xs, rot, scl, trn, gr, W0, b0, W1, b1, W2, b2, out);
        return;
    }

    char* ws = (char*)d_ws;
    uint2*    gridsP  = (uint2*)(ws);
    float4*   sorted  = (float4*)(ws + WS_SORT);
    unsigned* keyrank = (unsigned*)(ws + WS_KEYR);
    unsigned* bins    = (unsigned*)(ws + WS_BINS);
    float*    mats    = (float*)(ws + WS_MATS);
    uint4*    wpack   = (uint4*)(ws + WS_WPACK);
    unsigned* part    = (unsigned*)(ws + WS_PART);

    hipMemsetAsync(bins, 0, BINS_BYTES, stream);
    hipLaunchKernelGGL(prep_kernel, dim3(PREP_REPACK + PREP_HIST + 2), dim3(256), 0, stream,
                       gr, gridsP, xs, bins, keyrank,
                       rot, scl, trn, mats, W0, W1, wpack);
    hipLaunchKernelGGL(scanA_kernel, dim3(NBINS / 256), dim3(256), 0, stream, bins, part);
    hipLaunchKernelGGL(scanB_kernel, dim3(1), dim3(128), 0, stream, part);
    hipLaunchKernelGGL(scatter_kernel, dim3(NPTS / 256), dim3(256), 0, stream,
                       xs, bins, part, keyrank, sorted);
    hipLaunchKernelGGL(amgsrn_main, dim3(NPTS / 256), dim3(256), 0, stream,
                       sorted, gridsP, mats, wpack, b0, b1, W2, b2, out);
}